// Round 1
// baseline (1074.485 us; speedup 1.0000x reference)
//
#include <hip/hip_runtime.h>
#include <hip/hip_bf16.h>
#include <math.h>

#define T_LEN 4096
#define DIM   2048
#define NH    6
#define DK    256
#define DVh   512
#define KD    1536
#define VD    3072
#define CK    64
#define NCHK  (T_LEN / CK)

typedef __attribute__((ext_vector_type(8))) short bf16x8;
typedef __attribute__((ext_vector_type(4))) float f32x4;

__device__ __forceinline__ float silu_f(float v){ return v / (1.f + __expf(-v)); }

__device__ __forceinline__ unsigned short f2bf(float f) {
  unsigned int u = __float_as_uint(f);
  unsigned int r = u + 0x7FFFu + ((u >> 16) & 1u);
  return (unsigned short)(r >> 16);
}
__device__ __forceinline__ float bf2f(unsigned short s) {
  return __uint_as_float(((unsigned int)s) << 16);
}

// LDS-only barrier: drains lgkmcnt (cross-wave LDS visibility) but leaves
// global loads/stores in flight across the barrier (no vmcnt(0) drain).
// sched_barrier(0) on both sides pins compiler ordering (guide rule #18).
__device__ __forceinline__ void bar_lds() {
  __builtin_amdgcn_sched_barrier(0);
  asm volatile("s_waitcnt lgkmcnt(0)" ::: "memory");
  __builtin_amdgcn_s_barrier();
  __builtin_amdgcn_sched_barrier(0);
}

// ---------------- cast fp32 -> bf16 ----------------
__global__ __launch_bounds__(256) void cast_bf16(
    const float* __restrict__ in, unsigned short* __restrict__ out)
{
  int i = blockIdx.x * 256 + threadIdx.x;
  float4 v4 = ((const float4*)in)[i];
  ushort4 o4;
  o4.x = f2bf(v4.x); o4.y = f2bf(v4.y); o4.z = f2bf(v4.z); o4.w = f2bf(v4.w);
  ((ushort4*)out)[i] = o4;
}

// ---------------- transpose + cast: in[R][Cn] fp32 -> out[Cn][R] bf16 ----------------
__global__ __launch_bounds__(256) void tcast(
    const float* __restrict__ in, unsigned short* __restrict__ out, int R, int Cn)
{
  __shared__ float tile[32][33];
  int bx = blockIdx.x * 32;
  int by = blockIdx.y * 32;
  int tx = threadIdx.x & 31, ty = threadIdx.x >> 5;
#pragma unroll
  for (int i = 0; i < 32; i += 8)
    tile[ty + i][tx] = in[(size_t)(by + ty + i) * Cn + bx + tx];
  __syncthreads();
#pragma unroll
  for (int i = 0; i < 32; i += 8)
    out[(size_t)(bx + ty + i) * R + by + tx] = f2bf(tile[tx][ty + i]);
}

// ---------------- bf16 MFMA GEMM (m97 structure, validated R2/R3) ----------------
__global__ __launch_bounds__(256) void gemm_bt_bf16(
    const unsigned short* __restrict__ A, const unsigned short* __restrict__ BT,
    void* __restrict__ Cout, int M, int N, int K, int act)
{
  __shared__ unsigned short As[128 * 32];
  __shared__ unsigned short Bs[128 * 32];
  const int tid = threadIdx.x;
  const int bm = blockIdx.y * 128, bn = blockIdx.x * 128;
  const int lane = tid & 63, wave = tid >> 6;
  const int wm = (wave >> 1) * 64, wn = (wave & 1) * 64;
  const int fr = lane & 15, kq = lane >> 4;

  f32x4 acc[4][4];
#pragma unroll
  for (int i = 0; i < 4; ++i)
#pragma unroll
    for (int j = 0; j < 4; ++j) acc[i][j] = (f32x4){0.f, 0.f, 0.f, 0.f};

  const int r0 = tid >> 2, c0 = (tid & 3) * 8;
  const int r1 = r0 + 64;

  for (int k0 = 0; k0 < K; k0 += 32) {
    __builtin_amdgcn_global_load_lds(
        (const __attribute__((address_space(1))) unsigned int*)(A + (size_t)(bm + r0) * K + k0 + c0),
        (__attribute__((address_space(3))) unsigned int*)(As + r0 * 32 + c0), 16, 0, 0);
    __builtin_amdgcn_global_load_lds(
        (const __attribute__((address_space(1))) unsigned int*)(A + (size_t)(bm + r1) * K + k0 + c0),
        (__attribute__((address_space(3))) unsigned int*)(As + r1 * 32 + c0), 16, 0, 0);
    __builtin_amdgcn_global_load_lds(
        (const __attribute__((address_space(1))) unsigned int*)(BT + (size_t)(bn + r0) * K + k0 + c0),
        (__attribute__((address_space(3))) unsigned int*)(Bs + r0 * 32 + c0), 16, 0, 0);
    __builtin_amdgcn_global_load_lds(
        (const __attribute__((address_space(1))) unsigned int*)(BT + (size_t)(bn + r1) * K + k0 + c0),
        (__attribute__((address_space(3))) unsigned int*)(Bs + r1 * 32 + c0), 16, 0, 0);
    __syncthreads();

    bf16x8 af[4], bfr[4];
#pragma unroll
    for (int i = 0; i < 4; ++i)
      af[i] = *(const bf16x8*)(As + (wm + i * 16 + fr) * 32 + kq * 8);
#pragma unroll
    for (int j = 0; j < 4; ++j)
      bfr[j] = *(const bf16x8*)(Bs + (wn + j * 16 + fr) * 32 + kq * 8);
#pragma unroll
    for (int i = 0; i < 4; ++i)
#pragma unroll
      for (int j = 0; j < 4; ++j)
        acc[i][j] = __builtin_amdgcn_mfma_f32_16x16x32_bf16(af[i], bfr[j], acc[i][j], 0, 0, 0);
    __syncthreads();
  }

  if (act == 2) {
    unsigned short* C = (unsigned short*)Cout;
#pragma unroll
    for (int i = 0; i < 4; ++i) {
      int rbase = bm + wm + i * 16 + kq * 4;
#pragma unroll
      for (int r = 0; r < 4; ++r) {
        size_t rowoff = (size_t)(rbase + r) * N + bn + wn + fr;
#pragma unroll
        for (int j = 0; j < 4; ++j) C[rowoff + j * 16] = f2bf(acc[i][j][r]);
      }
    }
  } else {
    float* C = (float*)Cout;
#pragma unroll
    for (int i = 0; i < 4; ++i) {
      int rbase = bm + wm + i * 16 + kq * 4;
#pragma unroll
      for (int r = 0; r < 4; ++r) {
        size_t rowoff = (size_t)(rbase + r) * N + bn + wn + fr;
#pragma unroll
        for (int j = 0; j < 4; ++j) {
          float v = acc[i][j][r];
          if (act == 1) v = silu_f(v);
          C[rowoff + j * 16] = v;
        }
      }
    }
  }
}

// ---------------- dyn = tg @ gen_w2 ----------------
__global__ __launch_bounds__(256) void proj_dyn(
    const float* __restrict__ tg, const float* __restrict__ w2, float* __restrict__ dyn)
{
  int t = blockIdx.x, tid = threadIdx.x;
  float g = tg[(size_t)t * 256 + tid];
  float p[4];
#pragma unroll
  for (int j = 0; j < 4; ++j) p[j] = g * w2[tid * 4 + j];
#pragma unroll
  for (int j = 0; j < 4; ++j)
    for (int m = 32; m >= 1; m >>= 1) p[j] += __shfl_xor(p[j], m);
  __shared__ float red[4][4];
  if ((tid & 63) == 0) {
    int w = tid >> 6;
#pragma unroll
    for (int j = 0; j < 4; ++j) red[w][j] = p[j];
  }
  __syncthreads();
  if (tid < 4) dyn[(size_t)t * 4 + tid] = red[0][tid] + red[1][tid] + red[2][tid] + red[3][tid];
}

// ---------------- beta / raw decay log-gate g ----------------
__global__ __launch_bounds__(256) void proj_bg(
    const float* __restrict__ h, const float* __restrict__ Wb, const float* __restrict__ Wa,
    const float* __restrict__ A_log, const float* __restrict__ dt_bias,
    float* __restrict__ beta, float* __restrict__ gout)
{
  int t = blockIdx.x, tid = threadIdx.x;
  float pb[6], pa[6];
#pragma unroll
  for (int j = 0; j < 6; ++j) { pb[j] = 0.f; pa[j] = 0.f; }
  for (int d = tid; d < DIM; d += 256) {
    float hv = h[(size_t)t * DIM + d];
#pragma unroll
    for (int j = 0; j < 6; ++j) {
      pb[j] += hv * Wb[d * 6 + j];
      pa[j] += hv * Wa[d * 6 + j];
    }
  }
#pragma unroll
  for (int j = 0; j < 6; ++j)
    for (int m = 32; m >= 1; m >>= 1) { pb[j] += __shfl_xor(pb[j], m); pa[j] += __shfl_xor(pa[j], m); }
  __shared__ float rb[4][6], ra[4][6];
  if ((tid & 63) == 0) {
    int w = tid >> 6;
#pragma unroll
    for (int j = 0; j < 6; ++j) { rb[w][j] = pb[j]; ra[w][j] = pa[j]; }
  }
  __syncthreads();
  if (tid < 6) {
    int j = tid;
    float sb = rb[0][j] + rb[1][j] + rb[2][j] + rb[3][j];
    float sa = ra[0][j] + ra[1][j] + ra[2][j] + ra[3][j];
    beta[(size_t)t * 6 + j] = 1.f / (1.f + expf(-sb));
    float z = sa + dt_bias[j];
    float sp = (z > 20.f) ? z : log1pf(expf(z));
    gout[(size_t)t * 6 + j] = -expf(A_log[j]) * sp;   // raw log-gate (g < 0)
  }
}

// ---------------- causal dynamic conv + silu ----------------
__global__ __launch_bounds__(256) void conv_kernel(
    const float* __restrict__ x, const float* __restrict__ dyn,
    const float* __restrict__ cw, float* __restrict__ v)
{
  int c = blockIdx.x * 256 + threadIdx.x;
  int t = blockIdx.y;
  float4 w4 = ((const float4*)cw)[c];
  float d0 = dyn[t * 4 + 0], d1 = dyn[t * 4 + 1], d2 = dyn[t * 4 + 2], d3 = dyn[t * 4 + 3];
  float acc = (w4.w + d3) * x[(size_t)t * VD + c];
  if (t >= 1) acc += (w4.z + d2) * x[(size_t)(t - 1) * VD + c];
  if (t >= 2) acc += (w4.y + d1) * x[(size_t)(t - 2) * VD + c];
  if (t >= 3) acc += (w4.x + d0) * x[(size_t)(t - 3) * VD + c];
  v[(size_t)t * VD + c] = silu_f(acc);
}

// ---------------- l2norm(q)*scale, l2norm(k) in place ----------------
__global__ __launch_bounds__(64) void l2norm_qk(
    float* __restrict__ q, float* __restrict__ k)
{
  size_t base = (size_t)blockIdx.x * 256;
  int tid = threadIdx.x;
  float4 qv = ((float4*)(q + base))[tid];
  float4 kv = ((float4*)(k + base))[tid];
  float sq = qv.x*qv.x + qv.y*qv.y + qv.z*qv.z + qv.w*qv.w;
  float sk = kv.x*kv.x + kv.y*kv.y + kv.z*kv.z + kv.w*kv.w;
  for (int m = 32; m >= 1; m >>= 1) { sq += __shfl_xor(sq, m); sk += __shfl_xor(sk, m); }
  float rq = rsqrtf(sq + 1e-6f) * 0.0625f;   // fold DK^-0.5
  float rk = rsqrtf(sk + 1e-6f);
  qv.x *= rq; qv.y *= rq; qv.z *= rq; qv.w *= rq;
  kv.x *= rk; kv.y *= rk; kv.z *= rk; kv.w *= rk;
  ((float4*)(q + base))[tid] = qv;
  ((float4*)(k + base))[tid] = kv;
}

// ---------------- P1: within-chunk inclusive cumsum of g, gamma = exp(c_end) ----------------
__global__ __launch_bounds__(64) void cumsum_g(
    const float* __restrict__ g, float* __restrict__ c, float* __restrict__ gammas)
{
  int ch = blockIdx.x, h = blockIdx.y;
  int t0 = ch * CK;
  int lane = threadIdx.x;
  float cum = g[(size_t)(t0 + lane) * 6 + h];
  for (int off = 1; off < 64; off <<= 1) {
    float n = __shfl_up(cum, off);
    if (lane >= off) cum += n;
  }
  c[(size_t)h * T_LEN + t0 + lane] = cum;
  if (lane == 63) gammas[h * NCHK + ch] = __expf(cum);
}

// ---------------- P2a: Kbar/Qbar = exp(c_t) * {k,q}  (bf16, same layout) ----------------
__global__ __launch_bounds__(384) void scale_kq(
    const float* __restrict__ q, const float* __restrict__ k, const float* __restrict__ c,
    unsigned short* __restrict__ Qb, unsigned short* __restrict__ Kb)
{
  int t = blockIdx.x;
  int tid = threadIdx.x;           // float4 index within row (384 = KD/4)
  int h = tid >> 6;
  float w1 = __expf(c[(size_t)h * T_LEN + t]);
  size_t off = (size_t)t * KD + tid * 4;
  float4 qv = *(const float4*)(q + off);
  float4 kv = *(const float4*)(k + off);
  ushort4 qo, ko;
  qo.x = f2bf(w1 * qv.x); qo.y = f2bf(w1 * qv.y); qo.z = f2bf(w1 * qv.z); qo.w = f2bf(w1 * qv.w);
  ko.x = f2bf(w1 * kv.x); ko.y = f2bf(w1 * kv.y); ko.z = f2bf(w1 * kv.z); ko.w = f2bf(w1 * kv.w);
  *(ushort4*)(Qb + off) = qo;
  *(ushort4*)(Kb + off) = ko;
}

// ---------------- P2b: KhT[h][ch][kk][tt] = exp(c_end - c_t) * k[t][kk]  (bf16) ----------------
__global__ __launch_bounds__(256) void make_khT(
    const float* __restrict__ k, const float* __restrict__ c,
    unsigned short* __restrict__ KhT)
{
  int ch = blockIdx.x, h = blockIdx.y;
  int t0 = ch * CK;
  int tt = threadIdx.x & 63, ks = threadIdx.x >> 6;
  float cend = c[(size_t)h * T_LEN + t0 + 63];
  float w2 = __expf(cend - c[(size_t)h * T_LEN + t0 + tt]);
  size_t obase = ((size_t)(h * NCHK + ch)) * DK * CK;
#pragma unroll 8
  for (int kb2 = 0; kb2 < 64; ++kb2) {
    int kk = ks * 64 + kb2;
    float kv = k[(size_t)(t0 + tt) * KD + h * 256 + kk];
    KhT[obase + (size_t)kk * CK + tt] = f2bf(w2 * kv);
  }
}

// ---------------- P3: per (h,chunk): L = strict_tril(beta_t e^{c_t-c_j} k_t.k_j),
//                   P = tril(e^{c_t-c_j} q_t.k_j)  via MFMA ----------------
__global__ __launch_bounds__(256) void chunk_lp(
    const float* __restrict__ q, const float* __restrict__ k,
    const float* __restrict__ c, const float* __restrict__ beta,
    float* __restrict__ Lg, unsigned short* __restrict__ Pm)
{
  const int ch = blockIdx.x, h = blockIdx.y;
  const int t0 = ch * CK;
  const int tid = threadIdx.x;
  const int w = tid >> 6, lane = tid & 63, fr = lane & 15, kq = lane >> 4;
  __shared__ unsigned short kb[64][264];
  __shared__ unsigned short qb[64][264];
  __shared__ float cs[64], bs[64];
#pragma unroll
  for (int i = 0; i < 16; ++i) {
    int fi = tid + i * 256;
    int r = fi >> 6, d4 = fi & 63;
    float4 kv = *(const float4*)(k + (size_t)(t0 + r) * KD + h * 256 + d4 * 4);
    float4 qv = *(const float4*)(q + (size_t)(t0 + r) * KD + h * 256 + d4 * 4);
    ushort4 k4, q4;
    k4.x = f2bf(kv.x); k4.y = f2bf(kv.y); k4.z = f2bf(kv.z); k4.w = f2bf(kv.w);
    q4.x = f2bf(qv.x); q4.y = f2bf(qv.y); q4.z = f2bf(qv.z); q4.w = f2bf(qv.w);
    *(ushort4*)&kb[r][d4 * 4] = k4;
    *(ushort4*)&qb[r][d4 * 4] = q4;
  }
  if (tid < 64) {
    cs[tid] = c[(size_t)h * T_LEN + t0 + tid];
    bs[tid] = beta[(size_t)(t0 + tid) * 6 + h];
  }
  __syncthreads();

  f32x4 akk[4], aqk[4];
#pragma unroll
  for (int j = 0; j < 4; ++j) { akk[j] = (f32x4){0,0,0,0}; aqk[j] = (f32x4){0,0,0,0}; }
#pragma unroll
  for (int kt = 0; kt < 8; ++kt) {
    bf16x8 ak = *(const bf16x8*)&kb[16 * w + fr][kt * 32 + kq * 8];
    bf16x8 aq = *(const bf16x8*)&qb[16 * w + fr][kt * 32 + kq * 8];
#pragma unroll
    for (int j = 0; j < 4; ++j) {
      bf16x8 b = *(const bf16x8*)&kb[j * 16 + fr][kt * 32 + kq * 8];
      akk[j] = __builtin_amdgcn_mfma_f32_16x16x32_bf16(ak, b, akk[j], 0, 0, 0);
      aqk[j] = __builtin_amdgcn_mfma_f32_16x16x32_bf16(aq, b, aqk[j], 0, 0, 0);
    }
  }
  size_t base = ((size_t)(h * NCHK + ch)) * CK * CK;
#pragma unroll
  for (int j = 0; j < 4; ++j) {
#pragma unroll
    for (int r = 0; r < 4; ++r) {
      int t = 16 * w + kq * 4 + r, col = j * 16 + fr;
      float e = __expf(fminf(cs[t] - cs[col], 0.f));
      Lg[base + t * 64 + col] = (col < t) ? bs[t] * e * akk[j][r] : 0.f;
      Pm[base + t * 64 + col] = f2bf((col <= t) ? e * aqk[j][r] : 0.f);
    }
  }
}

// ---------------- P4: T' = (I+L)^{-1} diag(beta)  (bf16) ----------------
__global__ __launch_bounds__(64) void tri_inv(
    const float* __restrict__ Lg, const float* __restrict__ beta,
    unsigned short* __restrict__ Tm)
{
  const int ch = blockIdx.x, h = blockIdx.y;
  const size_t base = ((size_t)(h * NCHK + ch)) * CK * CK;
  const int j = threadIdx.x;
  __shared__ float Ll[64][65];
  __shared__ float Tl[64][65];
  for (int t = 0; t < 64; ++t) Ll[t][j] = Lg[base + t * 64 + j];
  __syncthreads();
  for (int t = 0; t < 64; ++t) {
    float s;
    if (j > t) s = 0.f;
    else if (j == t) s = 1.f;
    else {
      s = 0.f;
      for (int m = j; m < t; ++m) s -= Ll[t][m] * Tl[m][j];
    }
    Tl[t][j] = s;
  }
  float bj = beta[(size_t)(ch * 64 + j) * 6 + h];
  for (int t = 0; t < 64; ++t) Tm[base + t * 64 + j] = f2bf(Tl[t][j] * bj);
}

// ---------------- chunked gated delta-rule scan (MFMA) ----------------
// grid (32, 6): blockIdx.x = 16-col slice of DVh, blockIdx.y = head.
// State S[256][16] fp32 lives in MFMA accumulators: wave w owns rows 64w..64w+63.
// Latency-bound structure (1 block/CU, 1 wave/SIMD): so (a) barriers are
// lgkmcnt-only (global loads/stores stay in flight across them), (b) the
// critical-path Kbar/V fragments for chunk ch+1 are register double-buffered
// and issued during chunk ch, (c) hi/lo MFMA chains use split accumulators
// (depth 16 -> 8). Registers are free here: grid-limited, not VGPR-limited.
__global__ __launch_bounds__(256) void scan_chunk(
    const unsigned short* __restrict__ Kb,   // [T][KD] Kbar
    const unsigned short* __restrict__ Qb,   // [T][KD] Qbar
    const unsigned short* __restrict__ KhT,  // [H][NCHK][DK][CK]
    const unsigned short* __restrict__ Tm,   // [H][NCHK][CK][CK]
    const unsigned short* __restrict__ Pm,   // [H][NCHK][CK][CK]
    const float* __restrict__ gammas,        // [H][NCHK]
    float* __restrict__ VO)                  // [T][VD]: V in, O out (in place)
{
  const int h = blockIdx.y, sl = blockIdx.x;
  const int tid = threadIdx.x;
  const int w = tid >> 6, lane = tid & 63;
  const int fr = lane & 15, kq = lane >> 4;

  __shared__ unsigned short S0h[16][264];
  __shared__ unsigned short S0l[16][264];
  __shared__ unsigned short XT[16][72];
  __shared__ unsigned short DVT[16][72];

  f32x4 st[4];
#pragma unroll
  for (int i = 0; i < 4; ++i) st[i] = (f32x4){0.f, 0.f, 0.f, 0.f};

  const int colg = h * DVh + sl * 16 + fr;
  const size_t hc0 = (size_t)h * NCHK;

  bf16x8 kfA[8], kfB[8];
  float vlA[4], vlB[4];

#define PREF_KV(KF, VL, chn) do { \
    const unsigned short* krow_ = Kb + (size_t)((chn) * CK + 16 * w + fr) * KD + h * 256 + kq * 8; \
    _Pragma("unroll") \
    for (int kt = 0; kt < 8; ++kt) KF[kt] = *(const bf16x8*)(krow_ + kt * 32); \
    _Pragma("unroll") \
    for (int r = 0; r < 4; ++r) VL[r] = VO[(size_t)((chn) * CK + 16 * w + kq * 4 + r) * VD + colg]; \
  } while (0)

#define CHUNK_BODY(chx, KF, VL, KFN, VLN) do { \
    const int ch_ = (chx); \
    const int t0_ = ch_ * CK; \
    const size_t cb_ = hc0 + ch_; \
    /* this-chunk single-buffered fragments: issued at top, consumed mid/late chunk */ \
    bf16x8 qf[8]; \
    { const unsigned short* qrow_ = Qb + (size_t)(t0_ + 16 * w + fr) * KD + h * 256 + kq * 8; \
      _Pragma("unroll") \
      for (int kt = 0; kt < 8; ++kt) qf[kt] = *(const bf16x8*)(qrow_ + kt * 32); } \
    bf16x8 tf[2], pf[2]; \
    { const unsigned short* trow_ = Tm + (cb_ * CK + 16 * w + fr) * CK + kq * 8; \
      const unsigned short* prow_ = Pm + (cb_ * CK + 16 * w + fr) * CK + kq * 8; \
      tf[0] = *(const bf16x8*)(trow_); tf[1] = *(const bf16x8*)(trow_ + 32); \
      pf[0] = *(const bf16x8*)(prow_); pf[1] = *(const bf16x8*)(prow_ + 32); } \
    bf16x8 hfr[4][2]; \
    _Pragma("unroll") \
    for (int i = 0; i < 4; ++i) { \
      const unsigned short* hrow_ = KhT + (cb_ * DK + 64 * w + 16 * i + fr) * CK + kq * 8; \
      hfr[i][0] = *(const bf16x8*)(hrow_); hfr[i][1] = *(const bf16x8*)(hrow_ + 32); } \
    const float gam_ = gammas[cb_]; \
    /* stage S0 to LDS as bf16 hi+lo */ \
    _Pragma("unroll") \
    for (int i = 0; i < 4; ++i) { \
      ushort4 hi4, lo4; \
      float s0 = st[i][0], s1 = st[i][1], s2 = st[i][2], s3 = st[i][3]; \
      hi4.x = f2bf(s0); lo4.x = f2bf(s0 - bf2f(hi4.x)); \
      hi4.y = f2bf(s1); lo4.y = f2bf(s1 - bf2f(hi4.y)); \
      hi4.z = f2bf(s2); lo4.z = f2bf(s2 - bf2f(hi4.z)); \
      hi4.w = f2bf(s3); lo4.w = f2bf(s3 - bf2f(hi4.w)); \
      *(ushort4*)&S0h[fr][64 * w + 16 * i + kq * 4] = hi4; \
      *(ushort4*)&S0l[fr][64 * w + 16 * i + kq * 4] = lo4; } \
    /* prefetch next chunk's critical-path fragments (consumed after next bar) */ \
    { const int chn_ = (ch_ + 1 < NCHK) ? ch_ + 1 : ch_; PREF_KV(KFN, VLN, chn_); } \
    bar_lds(); \
    /* step 1: Y = Kbar S0 (split hi/lo accumulators); X = V - Y -> bf16 XT */ \
    { f32x4 yh = (f32x4){0.f,0.f,0.f,0.f}, yl = (f32x4){0.f,0.f,0.f,0.f}; \
      _Pragma("unroll") \
      for (int kt = 0; kt < 8; ++kt) { \
        bf16x8 bh_ = *(const bf16x8*)&S0h[fr][kt * 32 + kq * 8]; \
        bf16x8 bl_ = *(const bf16x8*)&S0l[fr][kt * 32 + kq * 8]; \
        yh = __builtin_amdgcn_mfma_f32_16x16x32_bf16(KF[kt], bh_, yh, 0, 0, 0); \
        yl = __builtin_amdgcn_mfma_f32_16x16x32_bf16(KF[kt], bl_, yl, 0, 0, 0); } \
      ushort4 x4; \
      x4.x = f2bf(VL[0] - (yh[0] + yl[0])); \
      x4.y = f2bf(VL[1] - (yh[1] + yl[1])); \
      x4.z = f2bf(VL[2] - (yh[2] + yl[2])); \
      x4.w = f2bf(VL[3] - (yh[3] + yl[3])); \
      *(ushort4*)&XT[fr][16 * w + kq * 4] = x4; } \
    bar_lds(); \
    /* step 2: DV = T' X -> bf16 DVT */ \
    { f32x4 d = (f32x4){0.f,0.f,0.f,0.f}; \
      _Pragma("unroll") \
      for (int kt = 0; kt < 2; ++kt) { \
        bf16x8 b_ = *(const bf16x8*)&XT[fr][kt * 32 + kq * 8]; \
        d = __builtin_amdgcn_mfma_f32_16x16x32_bf16(tf[kt], b_, d, 0, 0, 0); } \
      ushort4 d4; \
      d4.x = f2bf(d[0]); d4.y = f2bf(d[1]); d4.z = f2bf(d[2]); d4.w = f2bf(d[3]); \
      *(ushort4*)&DVT[fr][16 * w + kq * 4] = d4; } \
    bar_lds(); \
    /* step 3: O = Qbar S0 + P DV (three independent accumulator chains) */ \
    { f32x4 oh = (f32x4){0.f,0.f,0.f,0.f}, ol = (f32x4){0.f,0.f,0.f,0.f}, op = (f32x4){0.f,0.f,0.f,0.f}; \
      _Pragma("unroll") \
      for (int kt = 0; kt < 8; ++kt) { \
        bf16x8 bh_ = *(const bf16x8*)&S0h[fr][kt * 32 + kq * 8]; \
        bf16x8 bl_ = *(const bf16x8*)&S0l[fr][kt * 32 + kq * 8]; \
        oh = __builtin_amdgcn_mfma_f32_16x16x32_bf16(qf[kt], bh_, oh, 0, 0, 0); \
        ol = __builtin_amdgcn_mfma_f32_16x16x32_bf16(qf[kt], bl_, ol, 0, 0, 0); } \
      _Pragma("unroll") \
      for (int kt = 0; kt < 2; ++kt) { \
        bf16x8 b_ = *(const bf16x8*)&DVT[fr][kt * 32 + kq * 8]; \
        op = __builtin_amdgcn_mfma_f32_16x16x32_bf16(pf[kt], b_, op, 0, 0, 0); } \
      _Pragma("unroll") \
      for (int r = 0; r < 4; ++r) \
        VO[(size_t)(t0_ + 16 * w + kq * 4 + r) * VD + colg] = oh[r] + ol[r] + op[r]; } \
    /* step 4: S = gamma*S0 + Khat^T DV */ \
    _Pragma("unroll") \
    for (int i = 0; i < 4; ++i) { \
      st[i][0] *= gam_; st[i][1] *= gam_; st[i][2] *= gam_; st[i][3] *= gam_; \
      _Pragma("unroll") \
      for (int kt = 0; kt < 2; ++kt) { \
        bf16x8 b_ = *(const bf16x8*)&DVT[fr][kt * 32 + kq * 8]; \
        st[i] = __builtin_amdgcn_mfma_f32_16x16x32_bf16(hfr[i][kt], b_, st[i], 0, 0, 0); } } \
    bar_lds(); \
  } while (0)

  PREF_KV(kfA, vlA, 0);
  for (int ch = 0; ch < NCHK; ch += 2) {
    CHUNK_BODY(ch,     kfA, vlA, kfB, vlB);
    CHUNK_BODY(ch + 1, kfB, vlB, kfA, vlA);
  }
#undef CHUNK_BODY
#undef PREF_KV
}

// ---------------- gated RMSNorm ----------------
__global__ __launch_bounds__(256) void norm_gate(
    const float* __restrict__ o, const unsigned short* __restrict__ gate,
    const float* __restrict__ nw, unsigned short* __restrict__ out)
{
  int th = blockIdx.x, tid = threadIdx.x;
  size_t base = (size_t)th * DVh;
  float x0 = o[base + tid], x1 = o[base + 256 + tid];
  float ss = x0 * x0 + x1 * x1;
  for (int m = 32; m >= 1; m >>= 1) ss += __shfl_xor(ss, m);
  __shared__ float red[4];
  if ((tid & 63) == 0) red[tid >> 6] = ss;
  __syncthreads();
  float rms = rsqrtf((red[0] + red[1] + red[2] + red[3]) * (1.f / 512.f) + 1e-5f);
  float g0 = bf2f(gate[base + tid]), g1 = bf2f(gate[base + 256 + tid]);
  out[base + tid]       = f2bf(x0 * rms * nw[tid]       * silu_f(g0));
  out[base + 256 + tid] = f2bf(x1 * rms * nw[tid + 256] * silu_f(g1));
}

extern "C" void kernel_launch(void* const* d_in, const int* in_sizes, int n_in,
                              void* d_out, int out_size, void* d_ws, size_t ws_size,
                              hipStream_t stream)
{
  const float* h       = (const float*)d_in[0];
  const float* Wq      = (const float*)d_in[1];
  const float* Wk      = (const float*)d_in[2];
  const float* Wv      = (const float*)d_in[3];
  const float* Wb      = (const float*)d_in[4];
  const float* Wa      = (const float*)d_in[5];
  const float* Wg      = (const float*)d_in[6];
  const float* Wo      = (const float*)d_in[7];
  const float* A_log   = (const float*)d_in[8];
  const float* dt_bias = (const float*)d_in[9];
  const float* conv_w  = (const float*)d_in[10];
  const float* gen_w1  = (const float*)d_in[11];
  const float* gen_w2  = (const float*)d_in[12];
  const float* norm_w  = (const float*)d_in[13];
  float* out = (float*)d_out;

  const size_t TK = (size_t)T_LEN * KD, TV = (size_t)T_LEN * VD, TD = (size_t)T_LEN * DIM;

  float* ws   = (float*)d_ws;
  float* q    = ws;
  float* k    = q    + TK;
  float* x    = k    + TK;          // h@Wv conv input; region later reused (see aliases)
  float* v    = x    + TV;          // conv out; O written in place by scan
  float* tg   = v    + TV;          // T*256
  float* dyn  = tg   + (size_t)T_LEN * 256;
  float* beta = dyn  + (size_t)T_LEN * 4;
  float* g    = beta + (size_t)T_LEN * 6;
  float* c    = g    + (size_t)T_LEN * 6;       // [H][T]
  float* gam  = c    + (size_t)NH * T_LEN;      // [H][NCHK]
  float* fend = gam  + 512;
  unsigned short* bh      = (unsigned short*)fend;          // T*DIM
  unsigned short* wT      = bh      + TD;                   // DIM*VD
  unsigned short* gate_bf = wT      + (size_t)DIM * VD;     // T*VD
  unsigned short* go_bf   = gate_bf + TV;                   // T*VD
  // aliases (lifetime-disjoint):
  unsigned short* Kb_s  = bh;                 // Kbar: bh dead after projection GEMMs
  unsigned short* Qb_s  = (unsigned short*)x; // x region free after conv
  unsigned short* KhT_s = Qb_s + TK;
  unsigned short* Tm_s  = KhT_s + TK;         // H*NCHK*DK*CK == T*KD
  unsigned short* Pm_s  = Tm_s + (size_t)NH * NCHK * CK * CK;
  float* Lg = (float*)go_bf;                  // consumed before norm_gate writes go_bf

  dim3 blk(256);
  cast_bf16<<<(TD / 4) / 256, blk, 0, stream>>>(h, bh);
  tcast<<<dim3(KD / 32, DIM / 32), blk, 0, stream>>>(Wq, wT, DIM, KD);
  gemm_bt_bf16<<<dim3(KD / 128, T_LEN / 128), blk, 0, stream>>>(bh, wT, q, T_LEN, KD, DIM, 1);
  tcast<<<dim3(KD / 32, DIM / 32), blk, 0, stream>>>(Wk, wT, DIM, KD);
  gemm_bt_bf16<<<dim3(KD / 128, T_LEN / 128), blk, 0, stream>>>(bh, wT, k, T_LEN, KD, DIM, 1);
  tcast<<<dim3(VD / 32, DIM / 32), blk, 0, stream>>>(Wv, wT, DIM, VD);
  gemm_bt_bf16<<<dim3(VD / 128, T_LEN / 128), blk, 0, stream>>>(bh, wT, x, T_LEN, VD, DIM, 0);
  tcast<<<dim3(VD / 32, DIM / 32), blk, 0, stream>>>(Wg, wT, DIM, VD);
  gemm_bt_bf16<<<dim3(VD / 128, T_LEN / 128), blk, 0, stream>>>(bh, wT, gate_bf, T_LEN, VD, DIM, 2);
  tcast<<<dim3(256 / 32, DIM / 32), blk, 0, stream>>>(gen_w1, wT, DIM, 256);
  gemm_bt_bf16<<<dim3(256 / 128, T_LEN / 128), blk, 0, stream>>>(bh, wT, tg, T_LEN, 256, DIM, 1);

  proj_dyn<<<T_LEN, blk, 0, stream>>>(tg, gen_w2, dyn);
  proj_bg<<<T_LEN, blk, 0, stream>>>(h, Wb, Wa, A_log, dt_bias, beta, g);
  conv_kernel<<<dim3(VD / 256, T_LEN), blk, 0, stream>>>(x, dyn, conv_w, v);
  l2norm_qk<<<T_LEN * NH, 64, 0, stream>>>(q, k);

  cumsum_g<<<dim3(NCHK, NH), 64, 0, stream>>>(g, c, gam);
  scale_kq<<<T_LEN, 384, 0, stream>>>(q, k, c, Qb_s, Kb_s);
  make_khT<<<dim3(NCHK, NH), blk, 0, stream>>>(k, c, KhT_s);
  chunk_lp<<<dim3(NCHK, NH), blk, 0, stream>>>(q, k, c, beta, Lg, Pm_s);
  tri_inv<<<dim3(NCHK, NH), 64, 0, stream>>>(Lg, beta, Tm_s);

  scan_chunk<<<dim3(DVh / 16, NH), blk, 0, stream>>>(Kb_s, Qb_s, KhT_s, Tm_s, Pm_s, gam, v);

  norm_gate<<<T_LEN * NH, blk, 0, stream>>>(v, gate_bf, norm_w, go_bf);
  tcast<<<dim3(DIM / 32, VD / 32), blk, 0, stream>>>(Wo, wT, VD, DIM);
  gemm_bt_bf16<<<dim3(DIM / 128, T_LEN / 128), blk, 0, stream>>>(go_bf, wT, out, T_LEN, DIM, VD, 0);
}

// Round 2
// 1050.070 us; speedup vs baseline: 1.0233x; 1.0233x over previous
//
#include <hip/hip_runtime.h>
#include <hip/hip_bf16.h>
#include <math.h>

#define T_LEN 4096
#define DIM   2048
#define NH    6
#define DK    256
#define DVh   512
#define KD    1536
#define VD    3072
#define CK    64
#define NCHK  (T_LEN / CK)

typedef __attribute__((ext_vector_type(8))) short bf16x8;
typedef __attribute__((ext_vector_type(4))) float f32x4;

__device__ __forceinline__ float silu_f(float v){ return v / (1.f + __expf(-v)); }

__device__ __forceinline__ unsigned short f2bf(float f) {
  unsigned int u = __float_as_uint(f);
  unsigned int r = u + 0x7FFFu + ((u >> 16) & 1u);
  return (unsigned short)(r >> 16);
}
__device__ __forceinline__ float bf2f(unsigned short s) {
  return __uint_as_float(((unsigned int)s) << 16);
}

// LDS-only barrier: drains lgkmcnt (cross-wave LDS visibility) but leaves
// global loads/stores in flight across the barrier (no vmcnt(0) drain).
__device__ __forceinline__ void bar_lds() {
  __builtin_amdgcn_sched_barrier(0);
  asm volatile("s_waitcnt lgkmcnt(0)" ::: "memory");
  __builtin_amdgcn_s_barrier();
  __builtin_amdgcn_sched_barrier(0);
}

// ---------------- cast fp32 -> bf16 ----------------
__global__ __launch_bounds__(256) void cast_bf16(
    const float* __restrict__ in, unsigned short* __restrict__ out)
{
  int i = blockIdx.x * 256 + threadIdx.x;
  float4 v4 = ((const float4*)in)[i];
  ushort4 o4;
  o4.x = f2bf(v4.x); o4.y = f2bf(v4.y); o4.z = f2bf(v4.z); o4.w = f2bf(v4.w);
  ((ushort4*)out)[i] = o4;
}

// ---------------- transpose + cast: in[R][Cn] fp32 -> out[Cn][R] bf16 ----------------
__global__ __launch_bounds__(256) void tcast(
    const float* __restrict__ in, unsigned short* __restrict__ out, int R, int Cn)
{
  __shared__ float tile[32][33];
  int bx = blockIdx.x * 32;
  int by = blockIdx.y * 32;
  int tx = threadIdx.x & 31, ty = threadIdx.x >> 5;
#pragma unroll
  for (int i = 0; i < 32; i += 8)
    tile[ty + i][tx] = in[(size_t)(by + ty + i) * Cn + bx + tx];
  __syncthreads();
#pragma unroll
  for (int i = 0; i < 32; i += 8)
    out[(size_t)(bx + ty + i) * R + by + tx] = f2bf(tile[tx][ty + i]);
}

// ---------------- bf16 MFMA GEMM (m97 structure, validated R2/R3) ----------------
__global__ __launch_bounds__(256) void gemm_bt_bf16(
    const unsigned short* __restrict__ A, const unsigned short* __restrict__ BT,
    void* __restrict__ Cout, int M, int N, int K, int act)
{
  __shared__ unsigned short As[128 * 32];
  __shared__ unsigned short Bs[128 * 32];
  const int tid = threadIdx.x;
  const int bm = blockIdx.y * 128, bn = blockIdx.x * 128;
  const int lane = tid & 63, wave = tid >> 6;
  const int wm = (wave >> 1) * 64, wn = (wave & 1) * 64;
  const int fr = lane & 15, kq = lane >> 4;

  f32x4 acc[4][4];
#pragma unroll
  for (int i = 0; i < 4; ++i)
#pragma unroll
    for (int j = 0; j < 4; ++j) acc[i][j] = (f32x4){0.f, 0.f, 0.f, 0.f};

  const int r0 = tid >> 2, c0 = (tid & 3) * 8;
  const int r1 = r0 + 64;

  for (int k0 = 0; k0 < K; k0 += 32) {
    __builtin_amdgcn_global_load_lds(
        (const __attribute__((address_space(1))) unsigned int*)(A + (size_t)(bm + r0) * K + k0 + c0),
        (__attribute__((address_space(3))) unsigned int*)(As + r0 * 32 + c0), 16, 0, 0);
    __builtin_amdgcn_global_load_lds(
        (const __attribute__((address_space(1))) unsigned int*)(A + (size_t)(bm + r1) * K + k0 + c0),
        (__attribute__((address_space(3))) unsigned int*)(As + r1 * 32 + c0), 16, 0, 0);
    __builtin_amdgcn_global_load_lds(
        (const __attribute__((address_space(1))) unsigned int*)(BT + (size_t)(bn + r0) * K + k0 + c0),
        (__attribute__((address_space(3))) unsigned int*)(Bs + r0 * 32 + c0), 16, 0, 0);
    __builtin_amdgcn_global_load_lds(
        (const __attribute__((address_space(1))) unsigned int*)(BT + (size_t)(bn + r1) * K + k0 + c0),
        (__attribute__((address_space(3))) unsigned int*)(Bs + r1 * 32 + c0), 16, 0, 0);
    __syncthreads();

    bf16x8 af[4], bfr[4];
#pragma unroll
    for (int i = 0; i < 4; ++i)
      af[i] = *(const bf16x8*)(As + (wm + i * 16 + fr) * 32 + kq * 8);
#pragma unroll
    for (int j = 0; j < 4; ++j)
      bfr[j] = *(const bf16x8*)(Bs + (wn + j * 16 + fr) * 32 + kq * 8);
#pragma unroll
    for (int i = 0; i < 4; ++i)
#pragma unroll
      for (int j = 0; j < 4; ++j)
        acc[i][j] = __builtin_amdgcn_mfma_f32_16x16x32_bf16(af[i], bfr[j], acc[i][j], 0, 0, 0);
    __syncthreads();
  }

  if (act == 2) {
    unsigned short* C = (unsigned short*)Cout;
#pragma unroll
    for (int i = 0; i < 4; ++i) {
      int rbase = bm + wm + i * 16 + kq * 4;
#pragma unroll
      for (int r = 0; r < 4; ++r) {
        size_t rowoff = (size_t)(rbase + r) * N + bn + wn + fr;
#pragma unroll
        for (int j = 0; j < 4; ++j) C[rowoff + j * 16] = f2bf(acc[i][j][r]);
      }
    }
  } else {
    float* C = (float*)Cout;
#pragma unroll
    for (int i = 0; i < 4; ++i) {
      int rbase = bm + wm + i * 16 + kq * 4;
#pragma unroll
      for (int r = 0; r < 4; ++r) {
        size_t rowoff = (size_t)(rbase + r) * N + bn + wn + fr;
#pragma unroll
        for (int j = 0; j < 4; ++j) {
          float v = acc[i][j][r];
          if (act == 1) v = silu_f(v);
          C[rowoff + j * 16] = v;
        }
      }
    }
  }
}

// ---------------- dyn = tg @ gen_w2 ----------------
__global__ __launch_bounds__(256) void proj_dyn(
    const float* __restrict__ tg, const float* __restrict__ w2, float* __restrict__ dyn)
{
  int t = blockIdx.x, tid = threadIdx.x;
  float g = tg[(size_t)t * 256 + tid];
  float p[4];
#pragma unroll
  for (int j = 0; j < 4; ++j) p[j] = g * w2[tid * 4 + j];
#pragma unroll
  for (int j = 0; j < 4; ++j)
    for (int m = 32; m >= 1; m >>= 1) p[j] += __shfl_xor(p[j], m);
  __shared__ float red[4][4];
  if ((tid & 63) == 0) {
    int w = tid >> 6;
#pragma unroll
    for (int j = 0; j < 4; ++j) red[w][j] = p[j];
  }
  __syncthreads();
  if (tid < 4) dyn[(size_t)t * 4 + tid] = red[0][tid] + red[1][tid] + red[2][tid] + red[3][tid];
}

// ---------------- beta / raw decay log-gate g ----------------
__global__ __launch_bounds__(256) void proj_bg(
    const float* __restrict__ h, const float* __restrict__ Wb, const float* __restrict__ Wa,
    const float* __restrict__ A_log, const float* __restrict__ dt_bias,
    float* __restrict__ beta, float* __restrict__ gout)
{
  int t = blockIdx.x, tid = threadIdx.x;
  float pb[6], pa[6];
#pragma unroll
  for (int j = 0; j < 6; ++j) { pb[j] = 0.f; pa[j] = 0.f; }
  for (int d = tid; d < DIM; d += 256) {
    float hv = h[(size_t)t * DIM + d];
#pragma unroll
    for (int j = 0; j < 6; ++j) {
      pb[j] += hv * Wb[d * 6 + j];
      pa[j] += hv * Wa[d * 6 + j];
    }
  }
#pragma unroll
  for (int j = 0; j < 6; ++j)
    for (int m = 32; m >= 1; m >>= 1) { pb[j] += __shfl_xor(pb[j], m); pa[j] += __shfl_xor(pa[j], m); }
  __shared__ float rb[4][6], ra[4][6];
  if ((tid & 63) == 0) {
    int w = tid >> 6;
#pragma unroll
    for (int j = 0; j < 6; ++j) { rb[w][j] = pb[j]; ra[w][j] = pa[j]; }
  }
  __syncthreads();
  if (tid < 6) {
    int j = tid;
    float sb = rb[0][j] + rb[1][j] + rb[2][j] + rb[3][j];
    float sa = ra[0][j] + ra[1][j] + ra[2][j] + ra[3][j];
    beta[(size_t)t * 6 + j] = 1.f / (1.f + expf(-sb));
    float z = sa + dt_bias[j];
    float sp = (z > 20.f) ? z : log1pf(expf(z));
    gout[(size_t)t * 6 + j] = -expf(A_log[j]) * sp;   // raw log-gate (g < 0)
  }
}

// ---------------- causal dynamic conv + silu ----------------
__global__ __launch_bounds__(256) void conv_kernel(
    const float* __restrict__ x, const float* __restrict__ dyn,
    const float* __restrict__ cw, float* __restrict__ v)
{
  int c = blockIdx.x * 256 + threadIdx.x;
  int t = blockIdx.y;
  float4 w4 = ((const float4*)cw)[c];
  float d0 = dyn[t * 4 + 0], d1 = dyn[t * 4 + 1], d2 = dyn[t * 4 + 2], d3 = dyn[t * 4 + 3];
  float acc = (w4.w + d3) * x[(size_t)t * VD + c];
  if (t >= 1) acc += (w4.z + d2) * x[(size_t)(t - 1) * VD + c];
  if (t >= 2) acc += (w4.y + d1) * x[(size_t)(t - 2) * VD + c];
  if (t >= 3) acc += (w4.x + d0) * x[(size_t)(t - 3) * VD + c];
  v[(size_t)t * VD + c] = silu_f(acc);
}

// ---------------- l2norm(q)*scale, l2norm(k) in place ----------------
__global__ __launch_bounds__(64) void l2norm_qk(
    float* __restrict__ q, float* __restrict__ k)
{
  size_t base = (size_t)blockIdx.x * 256;
  int tid = threadIdx.x;
  float4 qv = ((float4*)(q + base))[tid];
  float4 kv = ((float4*)(k + base))[tid];
  float sq = qv.x*qv.x + qv.y*qv.y + qv.z*qv.z + qv.w*qv.w;
  float sk = kv.x*kv.x + kv.y*kv.y + kv.z*kv.z + kv.w*kv.w;
  for (int m = 32; m >= 1; m >>= 1) { sq += __shfl_xor(sq, m); sk += __shfl_xor(sk, m); }
  float rq = rsqrtf(sq + 1e-6f) * 0.0625f;   // fold DK^-0.5
  float rk = rsqrtf(sk + 1e-6f);
  qv.x *= rq; qv.y *= rq; qv.z *= rq; qv.w *= rq;
  kv.x *= rk; kv.y *= rk; kv.z *= rk; kv.w *= rk;
  ((float4*)(q + base))[tid] = qv;
  ((float4*)(k + base))[tid] = kv;
}

// ---------------- P1: within-chunk inclusive cumsum of g, gamma = exp(c_end) ----------------
__global__ __launch_bounds__(64) void cumsum_g(
    const float* __restrict__ g, float* __restrict__ c, float* __restrict__ gammas)
{
  int ch = blockIdx.x, h = blockIdx.y;
  int t0 = ch * CK;
  int lane = threadIdx.x;
  float cum = g[(size_t)(t0 + lane) * 6 + h];
  for (int off = 1; off < 64; off <<= 1) {
    float n = __shfl_up(cum, off);
    if (lane >= off) cum += n;
  }
  c[(size_t)h * T_LEN + t0 + lane] = cum;
  if (lane == 63) gammas[h * NCHK + ch] = __expf(cum);
}

// ---------------- P2a: Kbar/Qbar = exp(c_t) * {k,q}  (bf16, same layout) ----------------
__global__ __launch_bounds__(384) void scale_kq(
    const float* __restrict__ q, const float* __restrict__ k, const float* __restrict__ c,
    unsigned short* __restrict__ Qb, unsigned short* __restrict__ Kb)
{
  int t = blockIdx.x;
  int tid = threadIdx.x;           // float4 index within row (384 = KD/4)
  int h = tid >> 6;
  float w1 = __expf(c[(size_t)h * T_LEN + t]);
  size_t off = (size_t)t * KD + tid * 4;
  float4 qv = *(const float4*)(q + off);
  float4 kv = *(const float4*)(k + off);
  ushort4 qo, ko;
  qo.x = f2bf(w1 * qv.x); qo.y = f2bf(w1 * qv.y); qo.z = f2bf(w1 * qv.z); qo.w = f2bf(w1 * qv.w);
  ko.x = f2bf(w1 * kv.x); ko.y = f2bf(w1 * kv.y); ko.z = f2bf(w1 * kv.z); ko.w = f2bf(w1 * kv.w);
  *(ushort4*)(Qb + off) = qo;
  *(ushort4*)(Kb + off) = ko;
}

// ---------------- P2b: KhT[h][ch][kk][tt] = exp(c_end - c_t) * k[t][kk]  (bf16) ----------------
__global__ __launch_bounds__(256) void make_khT(
    const float* __restrict__ k, const float* __restrict__ c,
    unsigned short* __restrict__ KhT)
{
  int ch = blockIdx.x, h = blockIdx.y;
  int t0 = ch * CK;
  int tt = threadIdx.x & 63, ks = threadIdx.x >> 6;
  float cend = c[(size_t)h * T_LEN + t0 + 63];
  float w2 = __expf(cend - c[(size_t)h * T_LEN + t0 + tt]);
  size_t obase = ((size_t)(h * NCHK + ch)) * DK * CK;
#pragma unroll 8
  for (int kb2 = 0; kb2 < 64; ++kb2) {
    int kk = ks * 64 + kb2;
    float kv = k[(size_t)(t0 + tt) * KD + h * 256 + kk];
    KhT[obase + (size_t)kk * CK + tt] = f2bf(w2 * kv);
  }
}

// ---------------- P3: per (h,chunk): L = strict_tril(beta_t e^{c_t-c_j} k_t.k_j),
//                   P = tril(e^{c_t-c_j} q_t.k_j)  via MFMA ----------------
__global__ __launch_bounds__(256) void chunk_lp(
    const float* __restrict__ q, const float* __restrict__ k,
    const float* __restrict__ c, const float* __restrict__ beta,
    float* __restrict__ Lg, unsigned short* __restrict__ Pm)
{
  const int ch = blockIdx.x, h = blockIdx.y;
  const int t0 = ch * CK;
  const int tid = threadIdx.x;
  const int w = tid >> 6, lane = tid & 63, fr = lane & 15, kq = lane >> 4;
  __shared__ unsigned short kb[64][264];
  __shared__ unsigned short qb[64][264];
  __shared__ float cs[64], bs[64];
#pragma unroll
  for (int i = 0; i < 16; ++i) {
    int fi = tid + i * 256;
    int r = fi >> 6, d4 = fi & 63;
    float4 kv = *(const float4*)(k + (size_t)(t0 + r) * KD + h * 256 + d4 * 4);
    float4 qv = *(const float4*)(q + (size_t)(t0 + r) * KD + h * 256 + d4 * 4);
    ushort4 k4, q4;
    k4.x = f2bf(kv.x); k4.y = f2bf(kv.y); k4.z = f2bf(kv.z); k4.w = f2bf(kv.w);
    q4.x = f2bf(qv.x); q4.y = f2bf(qv.y); q4.z = f2bf(qv.z); q4.w = f2bf(qv.w);
    *(ushort4*)&kb[r][d4 * 4] = k4;
    *(ushort4*)&qb[r][d4 * 4] = q4;
  }
  if (tid < 64) {
    cs[tid] = c[(size_t)h * T_LEN + t0 + tid];
    bs[tid] = beta[(size_t)(t0 + tid) * 6 + h];
  }
  __syncthreads();

  f32x4 akk[4], aqk[4];
#pragma unroll
  for (int j = 0; j < 4; ++j) { akk[j] = (f32x4){0,0,0,0}; aqk[j] = (f32x4){0,0,0,0}; }
#pragma unroll
  for (int kt = 0; kt < 8; ++kt) {
    bf16x8 ak = *(const bf16x8*)&kb[16 * w + fr][kt * 32 + kq * 8];
    bf16x8 aq = *(const bf16x8*)&qb[16 * w + fr][kt * 32 + kq * 8];
#pragma unroll
    for (int j = 0; j < 4; ++j) {
      bf16x8 b = *(const bf16x8*)&kb[j * 16 + fr][kt * 32 + kq * 8];
      akk[j] = __builtin_amdgcn_mfma_f32_16x16x32_bf16(ak, b, akk[j], 0, 0, 0);
      aqk[j] = __builtin_amdgcn_mfma_f32_16x16x32_bf16(aq, b, aqk[j], 0, 0, 0);
    }
  }
  size_t base = ((size_t)(h * NCHK + ch)) * CK * CK;
#pragma unroll
  for (int j = 0; j < 4; ++j) {
#pragma unroll
    for (int r = 0; r < 4; ++r) {
      int t = 16 * w + kq * 4 + r, col = j * 16 + fr;
      float e = __expf(fminf(cs[t] - cs[col], 0.f));
      Lg[base + t * 64 + col] = (col < t) ? bs[t] * e * akk[j][r] : 0.f;
      Pm[base + t * 64 + col] = f2bf((col <= t) ? e * aqk[j][r] : 0.f);
    }
  }
}

// ---------------- P4: T' = (I+L)^{-1} diag(beta)  (bf16) ----------------
__global__ __launch_bounds__(64) void tri_inv(
    const float* __restrict__ Lg, const float* __restrict__ beta,
    unsigned short* __restrict__ Tm)
{
  const int ch = blockIdx.x, h = blockIdx.y;
  const size_t base = ((size_t)(h * NCHK + ch)) * CK * CK;
  const int j = threadIdx.x;
  __shared__ float Ll[64][65];
  __shared__ float Tl[64][65];
  for (int t = 0; t < 64; ++t) Ll[t][j] = Lg[base + t * 64 + j];
  __syncthreads();
  for (int t = 0; t < 64; ++t) {
    float s;
    if (j > t) s = 0.f;
    else if (j == t) s = 1.f;
    else {
      s = 0.f;
      for (int m = j; m < t; ++m) s -= Ll[t][m] * Tl[m][j];
    }
    Tl[t][j] = s;
  }
  float bj = beta[(size_t)(ch * 64 + j) * 6 + h];
  for (int t = 0; t < 64; ++t) Tm[base + t * 64 + j] = f2bf(Tl[t][j] * bj);
}

// ---------------- chunked gated delta-rule scan (MFMA) ----------------
// grid (32, 6): blockIdx.x = 16-col slice of DVh, blockIdx.y = head.
// State S[256][16] fp32 lives in MFMA accumulators: wave w owns rows 64w..64w+63.
// R2 restructure: the per-CU LDS pipe is the shared serialized resource
// (4 waves each re-read the full S0 hi/lo twice per chunk). So:
//  - FUSE Qbar*S0 into the Kbar*S0 loop (same B-fragments, read S0 ONCE),
//  - barriers 4 -> 3 (staging of next S0 fused into the state update),
//  - double-buffer qf alongside kf (qf now consumed at phase-1 top).
__global__ __launch_bounds__(256) void scan_chunk(
    const unsigned short* __restrict__ Kb,   // [T][KD] Kbar
    const unsigned short* __restrict__ Qb,   // [T][KD] Qbar
    const unsigned short* __restrict__ KhT,  // [H][NCHK][DK][CK]
    const unsigned short* __restrict__ Tm,   // [H][NCHK][CK][CK]
    const unsigned short* __restrict__ Pm,   // [H][NCHK][CK][CK]
    const float* __restrict__ gammas,        // [H][NCHK]
    float* __restrict__ VO)                  // [T][VD]: V in, O out (in place)
{
  const int h = blockIdx.y, sl = blockIdx.x;
  const int tid = threadIdx.x;
  const int w = tid >> 6, lane = tid & 63;
  const int fr = lane & 15, kq = lane >> 4;

  __shared__ unsigned short S0h[16][264];
  __shared__ unsigned short S0l[16][264];
  __shared__ unsigned short XT[16][72];
  __shared__ unsigned short DVT[16][72];

  f32x4 st[4];
#pragma unroll
  for (int i = 0; i < 4; ++i) st[i] = (f32x4){0.f, 0.f, 0.f, 0.f};

  const int colg = h * DVh + sl * 16 + fr;
  const size_t hc0 = (size_t)h * NCHK;

  // zero-init the S0 staging region (cols < 256 are the only ones read)
  {
    int zr = tid >> 4;          // 0..15
    int zc = (tid & 15) * 16;   // 0..240
    ushort4 z; z.x = 0; z.y = 0; z.z = 0; z.w = 0;
#pragma unroll
    for (int u = 0; u < 4; ++u) {
      *(ushort4*)&S0h[zr][zc + 4 * u] = z;
      *(ushort4*)&S0l[zr][zc + 4 * u] = z;
    }
  }

  bf16x8 kfA[8], kfB[8], qfA[8], qfB[8];
  float vlA[4], vlB[4];

#define PREF_KQV(KF, QF, VL, chn) do { \
    const unsigned short* krow_ = Kb + (size_t)((chn) * CK + 16 * w + fr) * KD + h * 256 + kq * 8; \
    const unsigned short* qrow_ = Qb + (size_t)((chn) * CK + 16 * w + fr) * KD + h * 256 + kq * 8; \
    _Pragma("unroll") \
    for (int kt = 0; kt < 8; ++kt) { \
      KF[kt] = *(const bf16x8*)(krow_ + kt * 32); \
      QF[kt] = *(const bf16x8*)(qrow_ + kt * 32); } \
    _Pragma("unroll") \
    for (int r = 0; r < 4; ++r) VL[r] = VO[(size_t)((chn) * CK + 16 * w + kq * 4 + r) * VD + colg]; \
  } while (0)

#define CHUNK_BODY(chx, KF, QF, VL, KFN, QFN, VLN) do { \
    const int ch_ = (chx); \
    const int t0_ = ch_ * CK; \
    const size_t cb_ = hc0 + ch_; \
    bf16x8 tf[2], pf[2]; \
    { const unsigned short* trow_ = Tm + (cb_ * CK + 16 * w + fr) * CK + kq * 8; \
      const unsigned short* prow_ = Pm + (cb_ * CK + 16 * w + fr) * CK + kq * 8; \
      tf[0] = *(const bf16x8*)(trow_); tf[1] = *(const bf16x8*)(trow_ + 32); \
      pf[0] = *(const bf16x8*)(prow_); pf[1] = *(const bf16x8*)(prow_ + 32); } \
    bf16x8 hfr[4][2]; \
    _Pragma("unroll") \
    for (int i = 0; i < 4; ++i) { \
      const unsigned short* hrow_ = KhT + (cb_ * DK + 64 * w + 16 * i + fr) * CK + kq * 8; \
      hfr[i][0] = *(const bf16x8*)(hrow_); hfr[i][1] = *(const bf16x8*)(hrow_ + 32); } \
    const float gam_ = gammas[cb_]; \
    /* prefetch next chunk's phase-1 fragments (double-buffered) */ \
    { const int chn_ = (ch_ + 1 < NCHK) ? ch_ + 1 : ch_; PREF_KQV(KFN, QFN, VLN, chn_); } \
    /* phase 1: Y = Kbar S0 and Oq = Qbar S0 FUSED on the same S0 B-frags; */ \
    /*          X = V - Y -> bf16 XT (4 independent 8-deep MFMA chains)    */ \
    f32x4 oh = (f32x4){0.f,0.f,0.f,0.f}, ol = (f32x4){0.f,0.f,0.f,0.f}; \
    { f32x4 yh = (f32x4){0.f,0.f,0.f,0.f}, yl = (f32x4){0.f,0.f,0.f,0.f}; \
      _Pragma("unroll") \
      for (int kt = 0; kt < 8; ++kt) { \
        bf16x8 bh_ = *(const bf16x8*)&S0h[fr][kt * 32 + kq * 8]; \
        bf16x8 bl_ = *(const bf16x8*)&S0l[fr][kt * 32 + kq * 8]; \
        yh = __builtin_amdgcn_mfma_f32_16x16x32_bf16(KF[kt], bh_, yh, 0, 0, 0); \
        yl = __builtin_amdgcn_mfma_f32_16x16x32_bf16(KF[kt], bl_, yl, 0, 0, 0); \
        oh = __builtin_amdgcn_mfma_f32_16x16x32_bf16(QF[kt], bh_, oh, 0, 0, 0); \
        ol = __builtin_amdgcn_mfma_f32_16x16x32_bf16(QF[kt], bl_, ol, 0, 0, 0); } \
      ushort4 x4; \
      x4.x = f2bf(VL[0] - (yh[0] + yl[0])); \
      x4.y = f2bf(VL[1] - (yh[1] + yl[1])); \
      x4.z = f2bf(VL[2] - (yh[2] + yl[2])); \
      x4.w = f2bf(VL[3] - (yh[3] + yl[3])); \
      *(ushort4*)&XT[fr][16 * w + kq * 4] = x4; } \
    bar_lds(); \
    /* phase 2: DV = T' X -> bf16 DVT */ \
    { f32x4 d = (f32x4){0.f,0.f,0.f,0.f}; \
      bf16x8 b0_ = *(const bf16x8*)&XT[fr][kq * 8]; \
      bf16x8 b1_ = *(const bf16x8*)&XT[fr][32 + kq * 8]; \
      d = __builtin_amdgcn_mfma_f32_16x16x32_bf16(tf[0], b0_, d, 0, 0, 0); \
      d = __builtin_amdgcn_mfma_f32_16x16x32_bf16(tf[1], b1_, d, 0, 0, 0); \
      ushort4 d4; \
      d4.x = f2bf(d[0]); d4.y = f2bf(d[1]); d4.z = f2bf(d[2]); d4.w = f2bf(d[3]); \
      *(ushort4*)&DVT[fr][16 * w + kq * 4] = d4; } \
    bar_lds(); \
    /* phase 3: O = (Qbar S0) + P DV, store; S = gamma*S0 + Khat^T DV; */ \
    /*          stage next S0 hi/lo to LDS fused with the state update  */ \
    { bf16x8 dv0_ = *(const bf16x8*)&DVT[fr][kq * 8]; \
      bf16x8 dv1_ = *(const bf16x8*)&DVT[fr][32 + kq * 8]; \
      f32x4 op = (f32x4){0.f,0.f,0.f,0.f}; \
      op = __builtin_amdgcn_mfma_f32_16x16x32_bf16(pf[0], dv0_, op, 0, 0, 0); \
      op = __builtin_amdgcn_mfma_f32_16x16x32_bf16(pf[1], dv1_, op, 0, 0, 0); \
      _Pragma("unroll") \
      for (int r = 0; r < 4; ++r) \
        VO[(size_t)(t0_ + 16 * w + kq * 4 + r) * VD + colg] = oh[r] + ol[r] + op[r]; \
      _Pragma("unroll") \
      for (int i = 0; i < 4; ++i) { \
        st[i][0] *= gam_; st[i][1] *= gam_; st[i][2] *= gam_; st[i][3] *= gam_; \
        st[i] = __builtin_amdgcn_mfma_f32_16x16x32_bf16(hfr[i][0], dv0_, st[i], 0, 0, 0); \
        st[i] = __builtin_amdgcn_mfma_f32_16x16x32_bf16(hfr[i][1], dv1_, st[i], 0, 0, 0); \
        ushort4 hi4, lo4; \
        { float s0 = st[i][0], s1 = st[i][1], s2 = st[i][2], s3 = st[i][3]; \
          hi4.x = f2bf(s0); lo4.x = f2bf(s0 - bf2f(hi4.x)); \
          hi4.y = f2bf(s1); lo4.y = f2bf(s1 - bf2f(hi4.y)); \
          hi4.z = f2bf(s2); lo4.z = f2bf(s2 - bf2f(hi4.z)); \
          hi4.w = f2bf(s3); lo4.w = f2bf(s3 - bf2f(hi4.w)); } \
        *(ushort4*)&S0h[fr][64 * w + 16 * i + kq * 4] = hi4; \
        *(ushort4*)&S0l[fr][64 * w + 16 * i + kq * 4] = lo4; } } \
    bar_lds(); \
  } while (0)

  PREF_KQV(kfA, qfA, vlA, 0);
  __syncthreads();   // covers the LDS zero-init
  for (int ch = 0; ch < NCHK; ch += 2) {
    CHUNK_BODY(ch,     kfA, qfA, vlA, kfB, qfB, vlB);
    CHUNK_BODY(ch + 1, kfB, qfB, vlB, kfA, qfA, vlA);
  }
#undef CHUNK_BODY
#undef PREF_KQV
}

// ---------------- gated RMSNorm ----------------
__global__ __launch_bounds__(256) void norm_gate(
    const float* __restrict__ o, const unsigned short* __restrict__ gate,
    const float* __restrict__ nw, unsigned short* __restrict__ out)
{
  int th = blockIdx.x, tid = threadIdx.x;
  size_t base = (size_t)th * DVh;
  float x0 = o[base + tid], x1 = o[base + 256 + tid];
  float ss = x0 * x0 + x1 * x1;
  for (int m = 32; m >= 1; m >>= 1) ss += __shfl_xor(ss, m);
  __shared__ float red[4];
  if ((tid & 63) == 0) red[tid >> 6] = ss;
  __syncthreads();
  float rms = rsqrtf((red[0] + red[1] + red[2] + red[3]) * (1.f / 512.f) + 1e-5f);
  float g0 = bf2f(gate[base + tid]), g1 = bf2f(gate[base + 256 + tid]);
  out[base + tid]       = f2bf(x0 * rms * nw[tid]       * silu_f(g0));
  out[base + 256 + tid] = f2bf(x1 * rms * nw[tid + 256] * silu_f(g1));
}

extern "C" void kernel_launch(void* const* d_in, const int* in_sizes, int n_in,
                              void* d_out, int out_size, void* d_ws, size_t ws_size,
                              hipStream_t stream)
{
  const float* h       = (const float*)d_in[0];
  const float* Wq      = (const float*)d_in[1];
  const float* Wk      = (const float*)d_in[2];
  const float* Wv      = (const float*)d_in[3];
  const float* Wb      = (const float*)d_in[4];
  const float* Wa      = (const float*)d_in[5];
  const float* Wg      = (const float*)d_in[6];
  const float* Wo      = (const float*)d_in[7];
  const float* A_log   = (const float*)d_in[8];
  const float* dt_bias = (const float*)d_in[9];
  const float* conv_w  = (const float*)d_in[10];
  const float* gen_w1  = (const float*)d_in[11];
  const float* gen_w2  = (const float*)d_in[12];
  const float* norm_w  = (const float*)d_in[13];
  float* out = (float*)d_out;

  const size_t TK = (size_t)T_LEN * KD, TV = (size_t)T_LEN * VD, TD = (size_t)T_LEN * DIM;

  float* ws   = (float*)d_ws;
  float* q    = ws;
  float* k    = q    + TK;
  float* x    = k    + TK;          // h@Wv conv input; region later reused (see aliases)
  float* v    = x    + TV;          // conv out; O written in place by scan
  float* tg   = v    + TV;          // T*256
  float* dyn  = tg   + (size_t)T_LEN * 256;
  float* beta = dyn  + (size_t)T_LEN * 4;
  float* g    = beta + (size_t)T_LEN * 6;
  float* c    = g    + (size_t)T_LEN * 6;       // [H][T]
  float* gam  = c    + (size_t)NH * T_LEN;      // [H][NCHK]
  float* fend = gam  + 512;
  unsigned short* bh      = (unsigned short*)fend;          // T*DIM
  unsigned short* wT      = bh      + TD;                   // DIM*VD
  unsigned short* gate_bf = wT      + (size_t)DIM * VD;     // T*VD
  unsigned short* go_bf   = gate_bf + TV;                   // T*VD
  // aliases (lifetime-disjoint):
  unsigned short* Kb_s  = bh;                 // Kbar: bh dead after projection GEMMs
  unsigned short* Qb_s  = (unsigned short*)x; // x region free after conv
  unsigned short* KhT_s = Qb_s + TK;
  unsigned short* Tm_s  = KhT_s + TK;         // H*NCHK*DK*CK == T*KD
  unsigned short* Pm_s  = Tm_s + (size_t)NH * NCHK * CK * CK;
  float* Lg = (float*)go_bf;                  // consumed before norm_gate writes go_bf

  dim3 blk(256);
  cast_bf16<<<(TD / 4) / 256, blk, 0, stream>>>(h, bh);
  tcast<<<dim3(KD / 32, DIM / 32), blk, 0, stream>>>(Wq, wT, DIM, KD);
  gemm_bt_bf16<<<dim3(KD / 128, T_LEN / 128), blk, 0, stream>>>(bh, wT, q, T_LEN, KD, DIM, 1);
  tcast<<<dim3(KD / 32, DIM / 32), blk, 0, stream>>>(Wk, wT, DIM, KD);
  gemm_bt_bf16<<<dim3(KD / 128, T_LEN / 128), blk, 0, stream>>>(bh, wT, k, T_LEN, KD, DIM, 1);
  tcast<<<dim3(VD / 32, DIM / 32), blk, 0, stream>>>(Wv, wT, DIM, VD);
  gemm_bt_bf16<<<dim3(VD / 128, T_LEN / 128), blk, 0, stream>>>(bh, wT, x, T_LEN, VD, DIM, 0);
  tcast<<<dim3(VD / 32, DIM / 32), blk, 0, stream>>>(Wg, wT, DIM, VD);
  gemm_bt_bf16<<<dim3(VD / 128, T_LEN / 128), blk, 0, stream>>>(bh, wT, gate_bf, T_LEN, VD, DIM, 2);
  tcast<<<dim3(256 / 32, DIM / 32), blk, 0, stream>>>(gen_w1, wT, DIM, 256);
  gemm_bt_bf16<<<dim3(256 / 128, T_LEN / 128), blk, 0, stream>>>(bh, wT, tg, T_LEN, 256, DIM, 1);

  proj_dyn<<<T_LEN, blk, 0, stream>>>(tg, gen_w2, dyn);
  proj_bg<<<T_LEN, blk, 0, stream>>>(h, Wb, Wa, A_log, dt_bias, beta, g);
  conv_kernel<<<dim3(VD / 256, T_LEN), blk, 0, stream>>>(x, dyn, conv_w, v);
  l2norm_qk<<<T_LEN * NH, 64, 0, stream>>>(q, k);

  cumsum_g<<<dim3(NCHK, NH), 64, 0, stream>>>(g, c, gam);
  scale_kq<<<T_LEN, 384, 0, stream>>>(q, k, c, Qb_s, Kb_s);
  make_khT<<<dim3(NCHK, NH), blk, 0, stream>>>(k, c, KhT_s);
  chunk_lp<<<dim3(NCHK, NH), blk, 0, stream>>>(q, k, c, beta, Lg, Pm_s);
  tri_inv<<<dim3(NCHK, NH), 64, 0, stream>>>(Lg, beta, Tm_s);

  scan_chunk<<<dim3(DVh / 16, NH), blk, 0, stream>>>(Kb_s, Qb_s, KhT_s, Tm_s, Pm_s, gam, v);

  norm_gate<<<T_LEN * NH, blk, 0, stream>>>(v, gate_bf, norm_w, go_bf);
  tcast<<<dim3(DIM / 32, VD / 32), blk, 0, stream>>>(Wo, wT, VD, DIM);
  gemm_bt_bf16<<<dim3(DIM / 128, T_LEN / 128), blk, 0, stream>>>(go_bf, wT, out, T_LEN, DIM, VD, 0);
}

// Round 3
// 1034.641 us; speedup vs baseline: 1.0385x; 1.0149x over previous
//
#include <hip/hip_runtime.h>
#include <hip/hip_bf16.h>
#include <math.h>

#define T_LEN 4096
#define DIM   2048
#define NH    6
#define DK    256
#define DVh   512
#define KD    1536
#define VD    3072
#define CK    64
#define NCHK  (T_LEN / CK)

typedef __attribute__((ext_vector_type(8))) short bf16x8;
typedef __attribute__((ext_vector_type(4))) float f32x4;

__device__ __forceinline__ float silu_f(float v){ return v / (1.f + __expf(-v)); }

__device__ __forceinline__ unsigned short f2bf(float f) {
  unsigned int u = __float_as_uint(f);
  unsigned int r = u + 0x7FFFu + ((u >> 16) & 1u);
  return (unsigned short)(r >> 16);
}
__device__ __forceinline__ float bf2f(unsigned short s) {
  return __uint_as_float(((unsigned int)s) << 16);
}

// LDS-only barrier: drains lgkmcnt (cross-wave LDS visibility) but leaves
// global loads/stores in flight across the barrier (no vmcnt(0) drain).
__device__ __forceinline__ void bar_lds() {
  __builtin_amdgcn_sched_barrier(0);
  asm volatile("s_waitcnt lgkmcnt(0)" ::: "memory");
  __builtin_amdgcn_s_barrier();
  __builtin_amdgcn_sched_barrier(0);
}

// ---------------- cast fp32 -> bf16 ----------------
__global__ __launch_bounds__(256) void cast_bf16(
    const float* __restrict__ in, unsigned short* __restrict__ out)
{
  int i = blockIdx.x * 256 + threadIdx.x;
  float4 v4 = ((const float4*)in)[i];
  ushort4 o4;
  o4.x = f2bf(v4.x); o4.y = f2bf(v4.y); o4.z = f2bf(v4.z); o4.w = f2bf(v4.w);
  ((ushort4*)out)[i] = o4;
}

// ---------------- transpose + cast: in[R][Cn] fp32 -> out[Cn][R] bf16 ----------------
__global__ __launch_bounds__(256) void tcast(
    const float* __restrict__ in, unsigned short* __restrict__ out, int R, int Cn)
{
  __shared__ float tile[32][33];
  int bx = blockIdx.x * 32;
  int by = blockIdx.y * 32;
  int tx = threadIdx.x & 31, ty = threadIdx.x >> 5;
#pragma unroll
  for (int i = 0; i < 32; i += 8)
    tile[ty + i][tx] = in[(size_t)(by + ty + i) * Cn + bx + tx];
  __syncthreads();
#pragma unroll
  for (int i = 0; i < 32; i += 8)
    out[(size_t)(bx + ty + i) * R + by + tx] = f2bf(tile[tx][ty + i]);
}

// ---------------- bf16 MFMA GEMM (m97 structure, validated R2/R3) ----------------
__global__ __launch_bounds__(256) void gemm_bt_bf16(
    const unsigned short* __restrict__ A, const unsigned short* __restrict__ BT,
    void* __restrict__ Cout, int M, int N, int K, int act)
{
  __shared__ unsigned short As[128 * 32];
  __shared__ unsigned short Bs[128 * 32];
  const int tid = threadIdx.x;
  const int bm = blockIdx.y * 128, bn = blockIdx.x * 128;
  const int lane = tid & 63, wave = tid >> 6;
  const int wm = (wave >> 1) * 64, wn = (wave & 1) * 64;
  const int fr = lane & 15, kq = lane >> 4;

  f32x4 acc[4][4];
#pragma unroll
  for (int i = 0; i < 4; ++i)
#pragma unroll
    for (int j = 0; j < 4; ++j) acc[i][j] = (f32x4){0.f, 0.f, 0.f, 0.f};

  const int r0 = tid >> 2, c0 = (tid & 3) * 8;
  const int r1 = r0 + 64;

  for (int k0 = 0; k0 < K; k0 += 32) {
    __builtin_amdgcn_global_load_lds(
        (const __attribute__((address_space(1))) unsigned int*)(A + (size_t)(bm + r0) * K + k0 + c0),
        (__attribute__((address_space(3))) unsigned int*)(As + r0 * 32 + c0), 16, 0, 0);
    __builtin_amdgcn_global_load_lds(
        (const __attribute__((address_space(1))) unsigned int*)(A + (size_t)(bm + r1) * K + k0 + c0),
        (__attribute__((address_space(3))) unsigned int*)(As + r1 * 32 + c0), 16, 0, 0);
    __builtin_amdgcn_global_load_lds(
        (const __attribute__((address_space(1))) unsigned int*)(BT + (size_t)(bn + r0) * K + k0 + c0),
        (__attribute__((address_space(3))) unsigned int*)(Bs + r0 * 32 + c0), 16, 0, 0);
    __builtin_amdgcn_global_load_lds(
        (const __attribute__((address_space(1))) unsigned int*)(BT + (size_t)(bn + r1) * K + k0 + c0),
        (__attribute__((address_space(3))) unsigned int*)(Bs + r1 * 32 + c0), 16, 0, 0);
    __syncthreads();

    bf16x8 af[4], bfr[4];
#pragma unroll
    for (int i = 0; i < 4; ++i)
      af[i] = *(const bf16x8*)(As + (wm + i * 16 + fr) * 32 + kq * 8);
#pragma unroll
    for (int j = 0; j < 4; ++j)
      bfr[j] = *(const bf16x8*)(Bs + (wn + j * 16 + fr) * 32 + kq * 8);
#pragma unroll
    for (int i = 0; i < 4; ++i)
#pragma unroll
      for (int j = 0; j < 4; ++j)
        acc[i][j] = __builtin_amdgcn_mfma_f32_16x16x32_bf16(af[i], bfr[j], acc[i][j], 0, 0, 0);
    __syncthreads();
  }

  if (act == 2) {
    unsigned short* C = (unsigned short*)Cout;
#pragma unroll
    for (int i = 0; i < 4; ++i) {
      int rbase = bm + wm + i * 16 + kq * 4;
#pragma unroll
      for (int r = 0; r < 4; ++r) {
        size_t rowoff = (size_t)(rbase + r) * N + bn + wn + fr;
#pragma unroll
        for (int j = 0; j < 4; ++j) C[rowoff + j * 16] = f2bf(acc[i][j][r]);
      }
    }
  } else {
    float* C = (float*)Cout;
#pragma unroll
    for (int i = 0; i < 4; ++i) {
      int rbase = bm + wm + i * 16 + kq * 4;
#pragma unroll
      for (int r = 0; r < 4; ++r) {
        size_t rowoff = (size_t)(rbase + r) * N + bn + wn + fr;
#pragma unroll
        for (int j = 0; j < 4; ++j) {
          float v = acc[i][j][r];
          if (act == 1) v = silu_f(v);
          C[rowoff + j * 16] = v;
        }
      }
    }
  }
}

// ---------------- dyn = tg @ gen_w2 ----------------
__global__ __launch_bounds__(256) void proj_dyn(
    const float* __restrict__ tg, const float* __restrict__ w2, float* __restrict__ dyn)
{
  int t = blockIdx.x, tid = threadIdx.x;
  float g = tg[(size_t)t * 256 + tid];
  float p[4];
#pragma unroll
  for (int j = 0; j < 4; ++j) p[j] = g * w2[tid * 4 + j];
#pragma unroll
  for (int j = 0; j < 4; ++j)
    for (int m = 32; m >= 1; m >>= 1) p[j] += __shfl_xor(p[j], m);
  __shared__ float red[4][4];
  if ((tid & 63) == 0) {
    int w = tid >> 6;
#pragma unroll
    for (int j = 0; j < 4; ++j) red[w][j] = p[j];
  }
  __syncthreads();
  if (tid < 4) dyn[(size_t)t * 4 + tid] = red[0][tid] + red[1][tid] + red[2][tid] + red[3][tid];
}

// ---------------- beta / raw decay log-gate g ----------------
__global__ __launch_bounds__(256) void proj_bg(
    const float* __restrict__ h, const float* __restrict__ Wb, const float* __restrict__ Wa,
    const float* __restrict__ A_log, const float* __restrict__ dt_bias,
    float* __restrict__ beta, float* __restrict__ gout)
{
  int t = blockIdx.x, tid = threadIdx.x;
  float pb[6], pa[6];
#pragma unroll
  for (int j = 0; j < 6; ++j) { pb[j] = 0.f; pa[j] = 0.f; }
  for (int d = tid; d < DIM; d += 256) {
    float hv = h[(size_t)t * DIM + d];
#pragma unroll
    for (int j = 0; j < 6; ++j) {
      pb[j] += hv * Wb[d * 6 + j];
      pa[j] += hv * Wa[d * 6 + j];
    }
  }
#pragma unroll
  for (int j = 0; j < 6; ++j)
    for (int m = 32; m >= 1; m >>= 1) { pb[j] += __shfl_xor(pb[j], m); pa[j] += __shfl_xor(pa[j], m); }
  __shared__ float rb[4][6], ra[4][6];
  if ((tid & 63) == 0) {
    int w = tid >> 6;
#pragma unroll
    for (int j = 0; j < 6; ++j) { rb[w][j] = pb[j]; ra[w][j] = pa[j]; }
  }
  __syncthreads();
  if (tid < 6) {
    int j = tid;
    float sb = rb[0][j] + rb[1][j] + rb[2][j] + rb[3][j];
    float sa = ra[0][j] + ra[1][j] + ra[2][j] + ra[3][j];
    beta[(size_t)t * 6 + j] = 1.f / (1.f + expf(-sb));
    float z = sa + dt_bias[j];
    float sp = (z > 20.f) ? z : log1pf(expf(z));
    gout[(size_t)t * 6 + j] = -expf(A_log[j]) * sp;   // raw log-gate (g < 0)
  }
}

// ---------------- causal dynamic conv + silu ----------------
__global__ __launch_bounds__(256) void conv_kernel(
    const float* __restrict__ x, const float* __restrict__ dyn,
    const float* __restrict__ cw, float* __restrict__ v)
{
  int c = blockIdx.x * 256 + threadIdx.x;
  int t = blockIdx.y;
  float4 w4 = ((const float4*)cw)[c];
  float d0 = dyn[t * 4 + 0], d1 = dyn[t * 4 + 1], d2 = dyn[t * 4 + 2], d3 = dyn[t * 4 + 3];
  float acc = (w4.w + d3) * x[(size_t)t * VD + c];
  if (t >= 1) acc += (w4.z + d2) * x[(size_t)(t - 1) * VD + c];
  if (t >= 2) acc += (w4.y + d1) * x[(size_t)(t - 2) * VD + c];
  if (t >= 3) acc += (w4.x + d0) * x[(size_t)(t - 3) * VD + c];
  v[(size_t)t * VD + c] = silu_f(acc);
}

// ---------------- l2norm(q)*scale, l2norm(k) in place ----------------
__global__ __launch_bounds__(64) void l2norm_qk(
    float* __restrict__ q, float* __restrict__ k)
{
  size_t base = (size_t)blockIdx.x * 256;
  int tid = threadIdx.x;
  float4 qv = ((float4*)(q + base))[tid];
  float4 kv = ((float4*)(k + base))[tid];
  float sq = qv.x*qv.x + qv.y*qv.y + qv.z*qv.z + qv.w*qv.w;
  float sk = kv.x*kv.x + kv.y*kv.y + kv.z*kv.z + kv.w*kv.w;
  for (int m = 32; m >= 1; m >>= 1) { sq += __shfl_xor(sq, m); sk += __shfl_xor(sk, m); }
  float rq = rsqrtf(sq + 1e-6f) * 0.0625f;   // fold DK^-0.5
  float rk = rsqrtf(sk + 1e-6f);
  qv.x *= rq; qv.y *= rq; qv.z *= rq; qv.w *= rq;
  kv.x *= rk; kv.y *= rk; kv.z *= rk; kv.w *= rk;
  ((float4*)(q + base))[tid] = qv;
  ((float4*)(k + base))[tid] = kv;
}

// ---------------- P1: within-chunk inclusive cumsum of g, gamma = exp(c_end) ----------------
__global__ __launch_bounds__(64) void cumsum_g(
    const float* __restrict__ g, float* __restrict__ c, float* __restrict__ gammas)
{
  int ch = blockIdx.x, h = blockIdx.y;
  int t0 = ch * CK;
  int lane = threadIdx.x;
  float cum = g[(size_t)(t0 + lane) * 6 + h];
  for (int off = 1; off < 64; off <<= 1) {
    float n = __shfl_up(cum, off);
    if (lane >= off) cum += n;
  }
  c[(size_t)h * T_LEN + t0 + lane] = cum;
  if (lane == 63) gammas[h * NCHK + ch] = __expf(cum);
}

// ---------------- P2a: Kbar/Qbar = exp(c_t) * {k,q}  (bf16, same layout) ----------------
__global__ __launch_bounds__(384) void scale_kq(
    const float* __restrict__ q, const float* __restrict__ k, const float* __restrict__ c,
    unsigned short* __restrict__ Qb, unsigned short* __restrict__ Kb)
{
  int t = blockIdx.x;
  int tid = threadIdx.x;           // float4 index within row (384 = KD/4)
  int h = tid >> 6;
  float w1 = __expf(c[(size_t)h * T_LEN + t]);
  size_t off = (size_t)t * KD + tid * 4;
  float4 qv = *(const float4*)(q + off);
  float4 kv = *(const float4*)(k + off);
  ushort4 qo, ko;
  qo.x = f2bf(w1 * qv.x); qo.y = f2bf(w1 * qv.y); qo.z = f2bf(w1 * qv.z); qo.w = f2bf(w1 * qv.w);
  ko.x = f2bf(w1 * kv.x); ko.y = f2bf(w1 * kv.y); ko.z = f2bf(w1 * kv.z); ko.w = f2bf(w1 * kv.w);
  *(ushort4*)(Qb + off) = qo;
  *(ushort4*)(Kb + off) = ko;
}

// ---------------- P2b: KhT[h][ch][kk][tt] = exp(c_end - c_t) * k[t][kk]  (bf16) ----------------
__global__ __launch_bounds__(256) void make_khT(
    const float* __restrict__ k, const float* __restrict__ c,
    unsigned short* __restrict__ KhT)
{
  int ch = blockIdx.x, h = blockIdx.y;
  int t0 = ch * CK;
  int tt = threadIdx.x & 63, ks = threadIdx.x >> 6;
  float cend = c[(size_t)h * T_LEN + t0 + 63];
  float w2 = __expf(cend - c[(size_t)h * T_LEN + t0 + tt]);
  size_t obase = ((size_t)(h * NCHK + ch)) * DK * CK;
#pragma unroll 8
  for (int kb2 = 0; kb2 < 64; ++kb2) {
    int kk = ks * 64 + kb2;
    float kv = k[(size_t)(t0 + tt) * KD + h * 256 + kk];
    KhT[obase + (size_t)kk * CK + tt] = f2bf(w2 * kv);
  }
}

// ---------------- P3: per (h,chunk): L = strict_tril(beta_t e^{c_t-c_j} k_t.k_j),
//                   P = tril(e^{c_t-c_j} q_t.k_j)  via MFMA ----------------
__global__ __launch_bounds__(256) void chunk_lp(
    const float* __restrict__ q, const float* __restrict__ k,
    const float* __restrict__ c, const float* __restrict__ beta,
    float* __restrict__ Lg, unsigned short* __restrict__ Pm)
{
  const int ch = blockIdx.x, h = blockIdx.y;
  const int t0 = ch * CK;
  const int tid = threadIdx.x;
  const int w = tid >> 6, lane = tid & 63, fr = lane & 15, kq = lane >> 4;
  __shared__ unsigned short kb[64][264];
  __shared__ unsigned short qb[64][264];
  __shared__ float cs[64], bs[64];
#pragma unroll
  for (int i = 0; i < 16; ++i) {
    int fi = tid + i * 256;
    int r = fi >> 6, d4 = fi & 63;
    float4 kv = *(const float4*)(k + (size_t)(t0 + r) * KD + h * 256 + d4 * 4);
    float4 qv = *(const float4*)(q + (size_t)(t0 + r) * KD + h * 256 + d4 * 4);
    ushort4 k4, q4;
    k4.x = f2bf(kv.x); k4.y = f2bf(kv.y); k4.z = f2bf(kv.z); k4.w = f2bf(kv.w);
    q4.x = f2bf(qv.x); q4.y = f2bf(qv.y); q4.z = f2bf(qv.z); q4.w = f2bf(qv.w);
    *(ushort4*)&kb[r][d4 * 4] = k4;
    *(ushort4*)&qb[r][d4 * 4] = q4;
  }
  if (tid < 64) {
    cs[tid] = c[(size_t)h * T_LEN + t0 + tid];
    bs[tid] = beta[(size_t)(t0 + tid) * 6 + h];
  }
  __syncthreads();

  f32x4 akk[4], aqk[4];
#pragma unroll
  for (int j = 0; j < 4; ++j) { akk[j] = (f32x4){0,0,0,0}; aqk[j] = (f32x4){0,0,0,0}; }
#pragma unroll
  for (int kt = 0; kt < 8; ++kt) {
    bf16x8 ak = *(const bf16x8*)&kb[16 * w + fr][kt * 32 + kq * 8];
    bf16x8 aq = *(const bf16x8*)&qb[16 * w + fr][kt * 32 + kq * 8];
#pragma unroll
    for (int j = 0; j < 4; ++j) {
      bf16x8 b = *(const bf16x8*)&kb[j * 16 + fr][kt * 32 + kq * 8];
      akk[j] = __builtin_amdgcn_mfma_f32_16x16x32_bf16(ak, b, akk[j], 0, 0, 0);
      aqk[j] = __builtin_amdgcn_mfma_f32_16x16x32_bf16(aq, b, aqk[j], 0, 0, 0);
    }
  }
  size_t base = ((size_t)(h * NCHK + ch)) * CK * CK;
#pragma unroll
  for (int j = 0; j < 4; ++j) {
#pragma unroll
    for (int r = 0; r < 4; ++r) {
      int t = 16 * w + kq * 4 + r, col = j * 16 + fr;
      float e = __expf(fminf(cs[t] - cs[col], 0.f));
      Lg[base + t * 64 + col] = (col < t) ? bs[t] * e * akk[j][r] : 0.f;
      Pm[base + t * 64 + col] = f2bf((col <= t) ? e * aqk[j][r] : 0.f);
    }
  }
}

// ---------------- P4: T' = (I+L)^{-1} diag(beta)  (bf16) ----------------
__global__ __launch_bounds__(64) void tri_inv(
    const float* __restrict__ Lg, const float* __restrict__ beta,
    unsigned short* __restrict__ Tm)
{
  const int ch = blockIdx.x, h = blockIdx.y;
  const size_t base = ((size_t)(h * NCHK + ch)) * CK * CK;
  const int j = threadIdx.x;
  __shared__ float Ll[64][65];
  __shared__ float Tl[64][65];
  for (int t = 0; t < 64; ++t) Ll[t][j] = Lg[base + t * 64 + j];
  __syncthreads();
  for (int t = 0; t < 64; ++t) {
    float s;
    if (j > t) s = 0.f;
    else if (j == t) s = 1.f;
    else {
      s = 0.f;
      for (int m = j; m < t; ++m) s -= Ll[t][m] * Tl[m][j];
    }
    Tl[t][j] = s;
  }
  float bj = beta[(size_t)(ch * 64 + j) * 6 + h];
  for (int t = 0; t < 64; ++t) Tm[base + t * 64 + j] = f2bf(Tl[t][j] * bj);
}

// ---------------- chunked gated delta-rule scan (MFMA, 8-wave) ----------------
// grid (32, 6): blockIdx.x = 16-col slice of DVh, blockIdx.y = head.
// R3 restructure: 8 waves (512 threads) = 4 t-groups (tw) x 2 K-groups (kg).
// State S[256][16] fp32 in accumulators: wave w owns DK rows 32w..32w+31
// (2 tiles of 16). Phase 1's DK=256 reduction is split across kg (128 each);
// partial Y/O exchanged through LDS (one f32x4 per lane). This halves each
// wave's critical path and puts 2 waves/SIMD so co-resident waves hide each
// other's stalls (R1/R2 showed single-wave reordering cannot).
// Role split: kg0 produces X and DV; kg1 owns the O-store. setprio(1) wraps
// MFMA clusters (T5: pays only with wave role diversity, which now exists).
__global__ __launch_bounds__(512, 2) void scan_chunk(
    const unsigned short* __restrict__ Kb,   // [T][KD] Kbar
    const unsigned short* __restrict__ Qb,   // [T][KD] Qbar
    const unsigned short* __restrict__ KhT,  // [H][NCHK][DK][CK]
    const unsigned short* __restrict__ Tm,   // [H][NCHK][CK][CK]
    const unsigned short* __restrict__ Pm,   // [H][NCHK][CK][CK]
    const float* __restrict__ gammas,        // [H][NCHK]
    float* __restrict__ VO)                  // [T][VD]: V in, O out (in place)
{
  const int h = blockIdx.y, sl = blockIdx.x;
  const int tid = threadIdx.x;
  const int w = tid >> 6, lane = tid & 63;
  const int tw = w & 3, kg = w >> 2;
  const int fr = lane & 15, kq = lane >> 4;

  __shared__ unsigned short S0h[16][264];
  __shared__ unsigned short S0l[16][264];
  __shared__ unsigned short XT[16][72];
  __shared__ unsigned short DVT[16][72];
  __shared__ float PY[2][4][16][20];   // partial Y, [kg][tw][fr][kq*4+r]
  __shared__ float PO[2][4][16][20];   // partial O

  f32x4 st[2];
  st[0] = (f32x4){0.f, 0.f, 0.f, 0.f};
  st[1] = (f32x4){0.f, 0.f, 0.f, 0.f};

  const int colg = h * DVh + sl * 16 + fr;
  const size_t hc0 = (size_t)h * NCHK;

  // zero-init S0 staging (cols 0..255 are the ones read)
  {
    int zr = tid >> 5;          // 0..15
    int zc = (tid & 31) * 8;    // 0..248
    ushort4 z; z.x = 0; z.y = 0; z.z = 0; z.w = 0;
    *(ushort4*)&S0h[zr][zc]     = z;
    *(ushort4*)&S0h[zr][zc + 4] = z;
    *(ushort4*)&S0l[zr][zc]     = z;
    *(ushort4*)&S0l[zr][zc + 4] = z;
  }

  bf16x8 kfA[4], kfB[4], qfA[4], qfB[4];
  float vlA[4], vlB[4];

#define PREF(KF, QF, VL, chn) do { \
    const unsigned short* kr_ = Kb + (size_t)((chn) * CK + 16 * tw + fr) * KD + h * 256 + kg * 128 + kq * 8; \
    const unsigned short* qr_ = Qb + (size_t)((chn) * CK + 16 * tw + fr) * KD + h * 256 + kg * 128 + kq * 8; \
    _Pragma("unroll") \
    for (int kt = 0; kt < 4; ++kt) { \
      KF[kt] = *(const bf16x8*)(kr_ + kt * 32); \
      QF[kt] = *(const bf16x8*)(qr_ + kt * 32); } \
    if (kg == 0) { \
      _Pragma("unroll") \
      for (int r = 0; r < 4; ++r) VL[r] = VO[(size_t)((chn) * CK + 16 * tw + kq * 4 + r) * VD + colg]; } \
  } while (0)

#define BODY(chx, KF, QF, VL, KFN, QFN, VLN) do { \
    const int ch_ = (chx); \
    const int t0_ = ch_ * CK; \
    const size_t cb_ = hc0 + ch_; \
    /* tpf: kg0 = T' rows (for DV), kg1 = P rows (for O) */ \
    bf16x8 tpf[2]; \
    { const unsigned short* b_ = (kg == 0 ? Tm : Pm) + (cb_ * CK + 16 * tw + fr) * CK + kq * 8; \
      tpf[0] = *(const bf16x8*)(b_); tpf[1] = *(const bf16x8*)(b_ + 32); } \
    bf16x8 hfr[2][2]; \
    _Pragma("unroll") \
    for (int i = 0; i < 2; ++i) { \
      const unsigned short* hr_ = KhT + (cb_ * DK + 32 * w + 16 * i + fr) * CK + kq * 8; \
      hfr[i][0] = *(const bf16x8*)(hr_); hfr[i][1] = *(const bf16x8*)(hr_ + 32); } \
    const float gam_ = gammas[cb_]; \
    { const int chn_ = (ch_ + 1 < NCHK) ? ch_ + 1 : ch_; PREF(KFN, QFN, VLN, chn_); } \
    /* P1: partial Y/O over this wave's half of DK (4 kt) */ \
    f32x4 yt, ot; \
    { f32x4 yh = (f32x4){0.f,0.f,0.f,0.f}, yl = yh, oh = yh, ol = yh; \
      __builtin_amdgcn_s_setprio(1); \
      _Pragma("unroll") \
      for (int kt = 0; kt < 4; ++kt) { \
        const int ka_ = (kg * 4 + kt) * 32 + kq * 8; \
        bf16x8 bh_ = *(const bf16x8*)&S0h[fr][ka_]; \
        bf16x8 bl_ = *(const bf16x8*)&S0l[fr][ka_]; \
        yh = __builtin_amdgcn_mfma_f32_16x16x32_bf16(KF[kt], bh_, yh, 0, 0, 0); \
        yl = __builtin_amdgcn_mfma_f32_16x16x32_bf16(KF[kt], bl_, yl, 0, 0, 0); \
        oh = __builtin_amdgcn_mfma_f32_16x16x32_bf16(QF[kt], bh_, oh, 0, 0, 0); \
        ol = __builtin_amdgcn_mfma_f32_16x16x32_bf16(QF[kt], bl_, ol, 0, 0, 0); } \
      __builtin_amdgcn_s_setprio(0); \
      yt = yh + yl; ot = oh + ol; } \
    *(f32x4*)&PY[kg][tw][fr][kq * 4] = yt; \
    *(f32x4*)&PO[kg][tw][fr][kq * 4] = ot; \
    bar_lds();   /* B1: partials visible */ \
    if (kg == 0) { \
      f32x4 yo = *(const f32x4*)&PY[1][tw][fr][kq * 4]; \
      ushort4 x4; \
      x4.x = f2bf(VL[0] - (yt[0] + yo[0])); \
      x4.y = f2bf(VL[1] - (yt[1] + yo[1])); \
      x4.z = f2bf(VL[2] - (yt[2] + yo[2])); \
      x4.w = f2bf(VL[3] - (yt[3] + yo[3])); \
      *(ushort4*)&XT[fr][16 * tw + kq * 4] = x4; \
    } else { \
      f32x4 oo = *(const f32x4*)&PO[0][tw][fr][kq * 4]; \
      ot[0] += oo[0]; ot[1] += oo[1]; ot[2] += oo[2]; ot[3] += oo[3]; } \
    bar_lds();   /* B2: XT visible */ \
    /* P2: DV = T' X (kg0 only) */ \
    if (kg == 0) { \
      f32x4 d = (f32x4){0.f,0.f,0.f,0.f}; \
      bf16x8 b0_ = *(const bf16x8*)&XT[fr][kq * 8]; \
      bf16x8 b1_ = *(const bf16x8*)&XT[fr][32 + kq * 8]; \
      d = __builtin_amdgcn_mfma_f32_16x16x32_bf16(tpf[0], b0_, d, 0, 0, 0); \
      d = __builtin_amdgcn_mfma_f32_16x16x32_bf16(tpf[1], b1_, d, 0, 0, 0); \
      ushort4 d4; \
      d4.x = f2bf(d[0]); d4.y = f2bf(d[1]); d4.z = f2bf(d[2]); d4.w = f2bf(d[3]); \
      *(ushort4*)&DVT[fr][16 * tw + kq * 4] = d4; } \
    bar_lds();   /* B3: DVT visible */ \
    /* P3: O-store (kg1), state update + S0 staging (all) */ \
    { bf16x8 dv0_ = *(const bf16x8*)&DVT[fr][kq * 8]; \
      bf16x8 dv1_ = *(const bf16x8*)&DVT[fr][32 + kq * 8]; \
      if (kg == 1) { \
        f32x4 op = (f32x4){0.f,0.f,0.f,0.f}; \
        op = __builtin_amdgcn_mfma_f32_16x16x32_bf16(tpf[0], dv0_, op, 0, 0, 0); \
        op = __builtin_amdgcn_mfma_f32_16x16x32_bf16(tpf[1], dv1_, op, 0, 0, 0); \
        _Pragma("unroll") \
        for (int r = 0; r < 4; ++r) \
          VO[(size_t)(t0_ + 16 * tw + kq * 4 + r) * VD + colg] = ot[r] + op[r]; } \
      __builtin_amdgcn_s_setprio(1); \
      _Pragma("unroll") \
      for (int i = 0; i < 2; ++i) { \
        st[i][0] *= gam_; st[i][1] *= gam_; st[i][2] *= gam_; st[i][3] *= gam_; \
        st[i] = __builtin_amdgcn_mfma_f32_16x16x32_bf16(hfr[i][0], dv0_, st[i], 0, 0, 0); \
        st[i] = __builtin_amdgcn_mfma_f32_16x16x32_bf16(hfr[i][1], dv1_, st[i], 0, 0, 0); \
        ushort4 hi4, lo4; \
        { float s0 = st[i][0], s1 = st[i][1], s2 = st[i][2], s3 = st[i][3]; \
          hi4.x = f2bf(s0); lo4.x = f2bf(s0 - bf2f(hi4.x)); \
          hi4.y = f2bf(s1); lo4.y = f2bf(s1 - bf2f(hi4.y)); \
          hi4.z = f2bf(s2); lo4.z = f2bf(s2 - bf2f(hi4.z)); \
          hi4.w = f2bf(s3); lo4.w = f2bf(s3 - bf2f(hi4.w)); } \
        *(ushort4*)&S0h[fr][32 * w + 16 * i + kq * 4] = hi4; \
        *(ushort4*)&S0l[fr][32 * w + 16 * i + kq * 4] = lo4; } \
      __builtin_amdgcn_s_setprio(0); } \
    bar_lds();   /* B4: S0 visible for next chunk */ \
  } while (0)

  PREF(kfA, qfA, vlA, 0);
  __syncthreads();   // covers the LDS zero-init
  for (int ch = 0; ch < NCHK; ch += 2) {
    BODY(ch,     kfA, qfA, vlA, kfB, qfB, vlB);
    BODY(ch + 1, kfB, qfB, vlB, kfA, qfA, vlA);
  }
#undef BODY
#undef PREF
}

// ---------------- gated RMSNorm ----------------
__global__ __launch_bounds__(256) void norm_gate(
    const float* __restrict__ o, const unsigned short* __restrict__ gate,
    const float* __restrict__ nw, unsigned short* __restrict__ out)
{
  int th = blockIdx.x, tid = threadIdx.x;
  size_t base = (size_t)th * DVh;
  float x0 = o[base + tid], x1 = o[base + 256 + tid];
  float ss = x0 * x0 + x1 * x1;
  for (int m = 32; m >= 1; m >>= 1) ss += __shfl_xor(ss, m);
  __shared__ float red[4];
  if ((tid & 63) == 0) red[tid >> 6] = ss;
  __syncthreads();
  float rms = rsqrtf((red[0] + red[1] + red[2] + red[3]) * (1.f / 512.f) + 1e-5f);
  float g0 = bf2f(gate[base + tid]), g1 = bf2f(gate[base + 256 + tid]);
  out[base + tid]       = f2bf(x0 * rms * nw[tid]       * silu_f(g0));
  out[base + 256 + tid] = f2bf(x1 * rms * nw[tid + 256] * silu_f(g1));
}

extern "C" void kernel_launch(void* const* d_in, const int* in_sizes, int n_in,
                              void* d_out, int out_size, void* d_ws, size_t ws_size,
                              hipStream_t stream)
{
  const float* h       = (const float*)d_in[0];
  const float* Wq      = (const float*)d_in[1];
  const float* Wk      = (const float*)d_in[2];
  const float* Wv      = (const float*)d_in[3];
  const float* Wb      = (const float*)d_in[4];
  const float* Wa      = (const float*)d_in[5];
  const float* Wg      = (const float*)d_in[6];
  const float* Wo      = (const float*)d_in[7];
  const float* A_log   = (const float*)d_in[8];
  const float* dt_bias = (const float*)d_in[9];
  const float* conv_w  = (const float*)d_in[10];
  const float* gen_w1  = (const float*)d_in[11];
  const float* gen_w2  = (const float*)d_in[12];
  const float* norm_w  = (const float*)d_in[13];
  float* out = (float*)d_out;

  const size_t TK = (size_t)T_LEN * KD, TV = (size_t)T_LEN * VD, TD = (size_t)T_LEN * DIM;

  float* ws   = (float*)d_ws;
  float* q    = ws;
  float* k    = q    + TK;
  float* x    = k    + TK;          // h@Wv conv input; region later reused (see aliases)
  float* v    = x    + TV;          // conv out; O written in place by scan
  float* tg   = v    + TV;          // T*256
  float* dyn  = tg   + (size_t)T_LEN * 256;
  float* beta = dyn  + (size_t)T_LEN * 4;
  float* g    = beta + (size_t)T_LEN * 6;
  float* c    = g    + (size_t)T_LEN * 6;       // [H][T]
  float* gam  = c    + (size_t)NH * T_LEN;      // [H][NCHK]
  float* fend = gam  + 512;
  unsigned short* bh      = (unsigned short*)fend;          // T*DIM
  unsigned short* wT      = bh      + TD;                   // DIM*VD
  unsigned short* gate_bf = wT      + (size_t)DIM * VD;     // T*VD
  unsigned short* go_bf   = gate_bf + TV;                   // T*VD
  // aliases (lifetime-disjoint):
  unsigned short* Kb_s  = bh;                 // Kbar: bh dead after projection GEMMs
  unsigned short* Qb_s  = (unsigned short*)x; // x region free after conv
  unsigned short* KhT_s = Qb_s + TK;
  unsigned short* Tm_s  = KhT_s + TK;         // H*NCHK*DK*CK == T*KD
  unsigned short* Pm_s  = Tm_s + (size_t)NH * NCHK * CK * CK;
  float* Lg = (float*)go_bf;                  // consumed before norm_gate writes go_bf

  dim3 blk(256);
  cast_bf16<<<(TD / 4) / 256, blk, 0, stream>>>(h, bh);
  tcast<<<dim3(KD / 32, DIM / 32), blk, 0, stream>>>(Wq, wT, DIM, KD);
  gemm_bt_bf16<<<dim3(KD / 128, T_LEN / 128), blk, 0, stream>>>(bh, wT, q, T_LEN, KD, DIM, 1);
  tcast<<<dim3(KD / 32, DIM / 32), blk, 0, stream>>>(Wk, wT, DIM, KD);
  gemm_bt_bf16<<<dim3(KD / 128, T_LEN / 128), blk, 0, stream>>>(bh, wT, k, T_LEN, KD, DIM, 1);
  tcast<<<dim3(VD / 32, DIM / 32), blk, 0, stream>>>(Wv, wT, DIM, VD);
  gemm_bt_bf16<<<dim3(VD / 128, T_LEN / 128), blk, 0, stream>>>(bh, wT, x, T_LEN, VD, DIM, 0);
  tcast<<<dim3(VD / 32, DIM / 32), blk, 0, stream>>>(Wg, wT, DIM, VD);
  gemm_bt_bf16<<<dim3(VD / 128, T_LEN / 128), blk, 0, stream>>>(bh, wT, gate_bf, T_LEN, VD, DIM, 2);
  tcast<<<dim3(256 / 32, DIM / 32), blk, 0, stream>>>(gen_w1, wT, DIM, 256);
  gemm_bt_bf16<<<dim3(256 / 128, T_LEN / 128), blk, 0, stream>>>(bh, wT, tg, T_LEN, 256, DIM, 1);

  proj_dyn<<<T_LEN, blk, 0, stream>>>(tg, gen_w2, dyn);
  proj_bg<<<T_LEN, blk, 0, stream>>>(h, Wb, Wa, A_log, dt_bias, beta, g);
  conv_kernel<<<dim3(VD / 256, T_LEN), blk, 0, stream>>>(x, dyn, conv_w, v);
  l2norm_qk<<<T_LEN * NH, 64, 0, stream>>>(q, k);

  cumsum_g<<<dim3(NCHK, NH), 64, 0, stream>>>(g, c, gam);
  scale_kq<<<T_LEN, 384, 0, stream>>>(q, k, c, Qb_s, Kb_s);
  make_khT<<<dim3(NCHK, NH), blk, 0, stream>>>(k, c, KhT_s);
  chunk_lp<<<dim3(NCHK, NH), blk, 0, stream>>>(q, k, c, beta, Lg, Pm_s);
  tri_inv<<<dim3(NCHK, NH), 64, 0, stream>>>(Lg, beta, Tm_s);

  scan_chunk<<<dim3(DVh / 16, NH), 512, 0, stream>>>(Kb_s, Qb_s, KhT_s, Tm_s, Pm_s, gam, v);

  norm_gate<<<T_LEN * NH, blk, 0, stream>>>(v, gate_bf, norm_w, go_bf);
  tcast<<<dim3(DIM / 32, VD / 32), blk, 0, stream>>>(Wo, wT, VD, DIM);
  gemm_bt_bf16<<<dim3(DIM / 128, T_LEN / 128), blk, 0, stream>>>(go_bf, wT, out, T_LEN, DIM, VD, 0);
}